// Round 14
// baseline (410.668 us; speedup 1.0000x reference)
//
#include <hip/hip_runtime.h>
#include <hip/hip_bf16.h>

// ---------------------------------------------------------------------------
// Gemma sliding-window attention layer, MI355X round 14.
// attn9: in-block KV-split. 8 waves = 2 heads x 2 qsub x 2 KV-halves;
// each half owns single-buffered K/V LDS (4x16KB); simple stage->sync->
// compute->sync loop (TLP hides drains: 16 waves/CU via launch_bounds(512,4));
// online-softmax states merged in LDS at the end.
// GEMMs / norm_rope / cvt frozen from round 10.
// ---------------------------------------------------------------------------

typedef __bf16 bf16x8 __attribute__((ext_vector_type(8)));
typedef __bf16 bf16x4 __attribute__((ext_vector_type(4)));
typedef float f32x4 __attribute__((ext_vector_type(4)));

#define NB 2
#define SEQ 2048
#define DMODEL 2048
#define NH 8
#define NKV 4
#define DHEAD 256
#define SWIN 1024

#define AS1 __attribute__((address_space(1)))
#define AS3 __attribute__((address_space(3)))

static __device__ __forceinline__ void gload_lds16(const void* g, void* l) {
    __builtin_amdgcn_global_load_lds((const AS1 void*)g, (AS3 void*)l, 16, 0, 0);
}

static __device__ __forceinline__ bf16x4 tr16(const __bf16* p) {
    bf16x4 r;
    asm volatile("ds_read_b64_tr_b16 %0, %1" : "=v"(r) : "v"((const AS3 __bf16*)p));
    return r;
}

// ------------------- merged f32->bf16 convert + RoPE table ------------------
__global__ void cvt_rope(const float* __restrict__ s0, const float* __restrict__ s1,
                         const float* __restrict__ s2, const float* __restrict__ s3,
                         const float* __restrict__ s4, __bf16* __restrict__ d0,
                         __bf16* __restrict__ d1, __bf16* __restrict__ d2,
                         __bf16* __restrict__ d3, __bf16* __restrict__ d4,
                         float* __restrict__ cosT, float* __restrict__ sinT) {
    if (blockIdx.x >= 20480) {
        int idx = (blockIdx.x - 20480) * 256 + threadIdx.x;   // < 262144
        int s = idx >> 7, i = idx & 127;
        float fr = (float)s * __expf(-(float)i * 0.0719557843f);  // ln(1e4)/128
        cosT[idx] = cosf(fr);
        sinT[idx] = sinf(fr);
        return;
    }
    int i = blockIdx.x * 256 + threadIdx.x;      // covers exactly 5242880
    const float* src; __bf16* dst;
    if (i < 2097152) { src = s0; dst = d0; }
    else if (i < 3145728) { i -= 2097152; src = s1; dst = d1; }
    else if (i < 3670016) { i -= 3145728; src = s2; dst = d2; }
    else if (i < 4194304) { i -= 3670016; src = s3; dst = d3; }
    else                  { i -= 4194304; src = s4; dst = d4; }
    f32x4 v = ((const f32x4*)src)[i];
    bf16x4 o;
#pragma unroll
    for (int j = 0; j < 4; ++j) o[j] = (__bf16)v[j];
    ((bf16x4*)dst)[i] = o;
}

// --------- GEMM 256x256, BK=64, 8-phase pipelined: C = A[M,K] * B[N,K]^T ---
template <int OUTBF16>
__global__ __launch_bounds__(512, 2)
void gemm_bt8(const __bf16* __restrict__ A, const __bf16* __restrict__ B,
              void* __restrict__ Cv, int M, int N, int K, int nbx) {
    __shared__ __align__(16) __bf16 sA[2][256 * 64];   // 64 KB
    __shared__ __align__(16) __bf16 sB[2][256 * 64];   // 64 KB
    const int tid = threadIdx.x;
    const int wave = tid >> 6, lane = tid & 63;
    const int lo = lane & 15, hi = lane >> 4;
    const int wm = wave >> 2, wn = wave & 3;
    const int qq = (int)gridDim.x >> 3;
    const int swz = ((int)blockIdx.x & 7) * qq + ((int)blockIdx.x >> 3);
    const int bx = swz % nbx, by = swz / nbx;
    const int brow = by * 256, bcol = bx * 256;
    const int xr = lo & 7;

    int aoff[4];
#pragma unroll
    for (int i = 0; i < 4; ++i) {
        int n = i * 512 + tid, r = n >> 3, s = n & 7;
        aoff[i] = r * K + ((s ^ (r & 7)) << 3);   // pre-swizzled global source
    }
    const __bf16* Ab = A + (size_t)brow * K;
    const __bf16* Bb = B + (size_t)bcol * K;

    auto stgA = [&](int bsel, int kt, int h) {
        const __bf16* ga = Ab + kt * 64;
#pragma unroll
        for (int ii = 0; ii < 2; ++ii) {
            int i = h + ii * 2;
            gload_lds16(ga + aoff[i], (char*)&sA[bsel][0] + (i * 512 + wave * 64) * 16);
        }
    };
    auto stgB = [&](int bsel, int kt, int h) {
        const __bf16* gb = Bb + kt * 64;
#pragma unroll
        for (int i = 2 * h; i < 2 * h + 2; ++i)
            gload_lds16(gb + aoff[i], (char*)&sB[bsel][0] + (i * 512 + wave * 64) * 16);
    };

    f32x4 acc[8][4] = {};
    const int nt = K >> 6;

    stgA(0, 0, 0); stgA(0, 0, 1); stgB(0, 0, 0); stgB(0, 0, 1);
    stgA(1, 1, 0); stgA(1, 1, 1); stgB(1, 1, 0); stgB(1, 1, 1);
    asm volatile("s_waitcnt vmcnt(8)" ::: "memory");   // tile0 landed
    __builtin_amdgcn_s_barrier();

    for (int t = 0; t < nt; ++t) {
        const int buf = t & 1;
        const bool pre = (t + 2 < nt);
        const __bf16* sa = &sA[buf][0];
        const __bf16* sb = &sB[buf][0];
        bf16x8 af[8], b0[4], b1[4];
        // ---- g0: ds_read A rows wm*128+0..63 (slots {0,2}) + B-nh0; MFMA Q0
#pragma unroll
        for (int m = 0; m < 4; ++m)
#pragma unroll
            for (int ks = 0; ks < 2; ++ks)
                af[m * 2 + ks] = *(const bf16x8*)&sa[(wm * 128 + m * 16 + lo) * 64 + (((ks * 4 + hi) ^ xr) << 3)];
#pragma unroll
        for (int n = 0; n < 2; ++n)
#pragma unroll
            for (int ks = 0; ks < 2; ++ks)
                b0[n * 2 + ks] = *(const bf16x8*)&sb[(wn * 64 + n * 16 + lo) * 64 + (((ks * 4 + hi) ^ xr) << 3)];
        __builtin_amdgcn_sched_barrier(0);
        __builtin_amdgcn_s_barrier();
        __builtin_amdgcn_s_setprio(1);
#pragma unroll
        for (int m = 0; m < 4; ++m)
#pragma unroll
            for (int n = 0; n < 2; ++n)
#pragma unroll
                for (int ks = 0; ks < 2; ++ks)
                    acc[m][n] = __builtin_amdgcn_mfma_f32_16x16x32_bf16(af[m * 2 + ks], b0[n * 2 + ks], acc[m][n], 0, 0, 0);
        __builtin_amdgcn_s_setprio(0);
        __builtin_amdgcn_sched_barrier(0);
        __builtin_amdgcn_s_barrier();
        // ---- g1: ds_read B-nh1; stage A-set0(t+2); MFMA Q1
#pragma unroll
        for (int n = 0; n < 2; ++n)
#pragma unroll
            for (int ks = 0; ks < 2; ++ks)
                b1[n * 2 + ks] = *(const bf16x8*)&sb[(wn * 64 + (n + 2) * 16 + lo) * 64 + (((ks * 4 + hi) ^ xr) << 3)];
        if (pre) stgA(buf, t + 2, 0);
        __builtin_amdgcn_sched_barrier(0);
        __builtin_amdgcn_s_barrier();
        __builtin_amdgcn_s_setprio(1);
#pragma unroll
        for (int m = 0; m < 4; ++m)
#pragma unroll
            for (int n = 0; n < 2; ++n)
#pragma unroll
                for (int ks = 0; ks < 2; ++ks)
                    acc[m][n + 2] = __builtin_amdgcn_mfma_f32_16x16x32_bf16(af[m * 2 + ks], b1[n * 2 + ks], acc[m][n + 2], 0, 0, 0);
        __builtin_amdgcn_s_setprio(0);
        __builtin_amdgcn_sched_barrier(0);
        __builtin_amdgcn_s_barrier();
        // ---- g2: ds_read A rows wm*128+64..127 (slots {1,3}); stage B{2,3}(t+2); MFMA Q2
#pragma unroll
        for (int m = 0; m < 4; ++m)
#pragma unroll
            for (int ks = 0; ks < 2; ++ks)
                af[m * 2 + ks] = *(const bf16x8*)&sa[(wm * 128 + (m + 4) * 16 + lo) * 64 + (((ks * 4 + hi) ^ xr) << 3)];
        if (pre) stgB(buf, t + 2, 1);
        __builtin_amdgcn_sched_barrier(0);
        __builtin_amdgcn_s_barrier();
        __builtin_amdgcn_s_setprio(1);
#pragma unroll
        for (int m = 0; m < 4; ++m)
#pragma unroll
            for (int n = 0; n < 2; ++n)
#pragma unroll
                for (int ks = 0; ks < 2; ++ks)
                    acc[m + 4][n + 2] = __builtin_amdgcn_mfma_f32_16x16x32_bf16(af[m * 2 + ks], b1[n * 2 + ks], acc[m + 4][n + 2], 0, 0, 0);
        __builtin_amdgcn_s_setprio(0);
        __builtin_amdgcn_sched_barrier(0);
        __builtin_amdgcn_s_barrier();
        // ---- g3: stage A-set1{1,3}+B{0,1}(t+2); MFMA Q3; vmcnt(8)
        if (pre) { stgA(buf, t + 2, 1); stgB(buf, t + 2, 0); }
        __builtin_amdgcn_sched_barrier(0);
        __builtin_amdgcn_s_setprio(1);
#pragma unroll
        for (int m = 0; m < 4; ++m)
#pragma unroll
            for (int n = 0; n < 2; ++n)
#pragma unroll
                for (int ks = 0; ks < 2; ++ks)
                    acc[m + 4][n] = __builtin_amdgcn_mfma_f32_16x16x32_bf16(af[m * 2 + ks], b0[n * 2 + ks], acc[m + 4][n], 0, 0, 0);
        __builtin_amdgcn_s_setprio(0);
        if (pre) asm volatile("s_waitcnt vmcnt(8)" ::: "memory");
        else     asm volatile("s_waitcnt vmcnt(0)" ::: "memory");
        __builtin_amdgcn_sched_barrier(0);
        __builtin_amdgcn_s_barrier();
    }

#pragma unroll
    for (int m = 0; m < 8; ++m) {
        int row = brow + wm * 128 + m * 16 + hi * 4;
#pragma unroll
        for (int n = 0; n < 4; ++n) {
            int col = bcol + wn * 64 + n * 16 + lo;
            if constexpr (OUTBF16) {
                __bf16* cp = (__bf16*)Cv + (size_t)row * N + col;
#pragma unroll
                for (int j = 0; j < 4; ++j)
                    cp[(size_t)j * N] = (__bf16)acc[m][n][j];
            } else {
                float* cp = (float*)Cv + (size_t)row * N + col;
#pragma unroll
                for (int j = 0; j < 4; ++j)
                    cp[(size_t)j * N] = acc[m][n][j];
            }
        }
    }
}

// --------- GEMM 256x128, BK=64, out-proj (full machine, frozen) ------------
__global__ __launch_bounds__(512, 2)
void gemm_bt8n(const __bf16* __restrict__ A, const __bf16* __restrict__ B,
               float* __restrict__ C, int M, int N, int K, int nbx) {
    __shared__ __align__(16) __bf16 sA[2][256 * 64];   // 64 KB
    __shared__ __align__(16) __bf16 sB[2][128 * 64];   // 32 KB
    const int tid = threadIdx.x;
    const int wave = tid >> 6, lane = tid & 63;
    const int lo = lane & 15, hi = lane >> 4;
    const int wm = wave >> 1, wn = wave & 1;
    const int qq = (int)gridDim.x >> 3;
    const int swz = ((int)blockIdx.x & 7) * qq + ((int)blockIdx.x >> 3);
    const int bx = swz % nbx, by = swz / nbx;
    const int brow = by * 256, bcol = bx * 128;
    const int xr = lo & 7;

    int aoff[4], boff[2];
#pragma unroll
    for (int i = 0; i < 4; ++i) {
        int n = i * 512 + tid, r = n >> 3, s = n & 7;
        aoff[i] = r * K + ((s ^ (r & 7)) << 3);
    }
#pragma unroll
    for (int i = 0; i < 2; ++i) {
        int n = i * 512 + tid, r = n >> 3, s = n & 7;
        boff[i] = r * K + ((s ^ (r & 7)) << 3);
    }
    const __bf16* Ab = A + (size_t)brow * K;
    const __bf16* Bb = B + (size_t)bcol * K;

    auto stgAall = [&](int bsel, int kt) {
        const __bf16* ga = Ab + kt * 64;
#pragma unroll
        for (int i = 0; i < 4; ++i)
            gload_lds16(ga + aoff[i], (char*)&sA[bsel][0] + (i * 512 + wave * 64) * 16);
    };
    auto stgBall = [&](int bsel, int kt) {
        const __bf16* gb = Bb + kt * 64;
#pragma unroll
        for (int i = 0; i < 2; ++i)
            gload_lds16(gb + boff[i], (char*)&sB[bsel][0] + (i * 512 + wave * 64) * 16);
    };

    f32x4 acc[4][4] = {};
    const int nt = K >> 6;

    stgAall(0, 0); stgBall(0, 0);      // 6 loads (tile0)
    stgAall(1, 1); stgBall(1, 1);      // 6 loads (tile1)
    asm volatile("s_waitcnt vmcnt(6)" ::: "memory");   // tile0 landed
    __builtin_amdgcn_s_barrier();

    for (int t = 0; t < nt; ++t) {
        const int buf = t & 1;
        const bool pre = (t + 2 < nt);
        const __bf16* sa = &sA[buf][0];
        const __bf16* sb = &sB[buf][0];
        bf16x8 af[4], b0[4], b1[4];
        // ---- g0: ds_read A m01 + B n01; MFMA Q0
#pragma unroll
        for (int m = 0; m < 2; ++m)
#pragma unroll
            for (int ks = 0; ks < 2; ++ks)
                af[m * 2 + ks] = *(const bf16x8*)&sa[(wm * 64 + m * 16 + lo) * 64 + (((ks * 4 + hi) ^ xr) << 3)];
#pragma unroll
        for (int n = 0; n < 2; ++n)
#pragma unroll
            for (int ks = 0; ks < 2; ++ks)
                b0[n * 2 + ks] = *(const bf16x8*)&sb[(wn * 64 + n * 16 + lo) * 64 + (((ks * 4 + hi) ^ xr) << 3)];
        __builtin_amdgcn_sched_barrier(0);
        __builtin_amdgcn_s_barrier();
        __builtin_amdgcn_s_setprio(1);
#pragma unroll
        for (int m = 0; m < 2; ++m)
#pragma unroll
            for (int n = 0; n < 2; ++n)
#pragma unroll
                for (int ks = 0; ks < 2; ++ks)
                    acc[m][n] = __builtin_amdgcn_mfma_f32_16x16x32_bf16(af[m * 2 + ks], b0[n * 2 + ks], acc[m][n], 0, 0, 0);
        __builtin_amdgcn_s_setprio(0);
        __builtin_amdgcn_sched_barrier(0);
        __builtin_amdgcn_s_barrier();
        // ---- g1: ds_read B n23; MFMA Q1
#pragma unroll
        for (int n = 0; n < 2; ++n)
#pragma unroll
            for (int ks = 0; ks < 2; ++ks)
                b1[n * 2 + ks] = *(const bf16x8*)&sb[(wn * 64 + (n + 2) * 16 + lo) * 64 + (((ks * 4 + hi) ^ xr) << 3)];
        __builtin_amdgcn_sched_barrier(0);
        __builtin_amdgcn_s_barrier();
        __builtin_amdgcn_s_setprio(1);
#pragma unroll
        for (int m = 0; m < 2; ++m)
#pragma unroll
            for (int n = 0; n < 2; ++n)
#pragma unroll
                for (int ks = 0; ks < 2; ++ks)
                    acc[m][n + 2] = __builtin_amdgcn_mfma_f32_16x16x32_bf16(af[m * 2 + ks], b1[n * 2 + ks], acc[m][n + 2], 0, 0, 0);
        __builtin_amdgcn_s_setprio(0);
        __builtin_amdgcn_sched_barrier(0);
        __builtin_amdgcn_s_barrier();
        // ---- g2: ds_read A m23; stage B(t+2); MFMA Q2
#pragma unroll
        for (int m = 0; m < 2; ++m)
#pragma unroll
            for (int ks = 0; ks < 2; ++ks)
                af[m * 2 + ks] = *(const bf16x8*)&sa[(wm * 64 + (m + 2) * 16 + lo) * 64 + (((ks * 4 + hi) ^ xr) << 3)];
        if (pre) stgBall(buf, t + 2);
        __builtin_amdgcn_sched_barrier(0);
        __builtin_amdgcn_s_barrier();
        __builtin_amdgcn_s_setprio(1);
#pragma unroll
        for (int m = 0; m < 2; ++m)
#pragma unroll
            for (int n = 0; n < 2; ++n)
#pragma unroll
                for (int ks = 0; ks < 2; ++ks)
                    acc[m + 2][n + 2] = __builtin_amdgcn_mfma_f32_16x16x32_bf16(af[m * 2 + ks], b1[n * 2 + ks], acc[m + 2][n + 2], 0, 0, 0);
        __builtin_amdgcn_s_setprio(0);
        __builtin_amdgcn_sched_barrier(0);
        __builtin_amdgcn_s_barrier();
        // ---- g3: stage A(t+2); MFMA Q3; vmcnt(6)
        if (pre) stgAall(buf, t + 2);
        __builtin_amdgcn_sched_barrier(0);
        __builtin_amdgcn_s_setprio(1);
#pragma unroll
        for (int m = 0; m < 2; ++m)
#pragma unroll
            for (int n = 0; n < 2; ++n)
#pragma unroll
                for (int ks = 0; ks < 2; ++ks)
                    acc[m + 2][n] = __builtin_amdgcn_mfma_f32_16x16x32_bf16(af[m * 2 + ks], b0[n * 2 + ks], acc[m + 2][n], 0, 0, 0);
        __builtin_amdgcn_s_setprio(0);
        if (pre) asm volatile("s_waitcnt vmcnt(6)" ::: "memory");
        else     asm volatile("s_waitcnt vmcnt(0)" ::: "memory");
        __builtin_amdgcn_sched_barrier(0);
        __builtin_amdgcn_s_barrier();
    }

#pragma unroll
    for (int m = 0; m < 4; ++m) {
        int row = brow + wm * 64 + m * 16 + hi * 4;
#pragma unroll
        for (int n = 0; n < 4; ++n) {
            float* cp = C + (size_t)row * N + bcol + wn * 64 + n * 16 + lo;
#pragma unroll
            for (int j = 0; j < 4; ++j)
                cp[(size_t)j * N] = acc[m][n][j];
        }
    }
}

// ---------- RMSNorm + RoPE (q,k) + V copy, from QKV bf16 (frozen) ----------
__global__ __launch_bounds__(256)
void norm_rope(const __bf16* __restrict__ QKV, const float* __restrict__ qw,
               const float* __restrict__ kw, const float* __restrict__ cosT,
               const float* __restrict__ sinT, __bf16* __restrict__ Qo,
               __bf16* __restrict__ Ko, __bf16* __restrict__ Vo) {
    const int r = blockIdx.x;            // b*S + s
    const int b = r >> 11, s = r & (SEQ - 1);
    const int wave = threadIdx.x >> 6, lane = threadIdx.x & 63;
    f32x4 cos4 = *(const f32x4*)&cosT[s * 128 + (lane & 31) * 4];
    f32x4 sin4 = *(const f32x4*)&sinT[s * 128 + (lane & 31) * 4];
#pragma unroll
    for (int ii = 0; ii < 4; ++ii) {
        int hh = wave + ii * 4;          // 0..15
        if (hh < 12) {
            bool isq = hh < 8;
            int col0 = isq ? hh * DHEAD : DMODEL + (hh - 8) * DHEAD;
            const __bf16* src = QKV + (size_t)r * 4096 + col0;
            bf16x4 xb = *(const bf16x4*)&src[lane * 4];
            float x[4];
#pragma unroll
            for (int j = 0; j < 4; ++j) x[j] = (float)xb[j];
            float ss = x[0] * x[0] + x[1] * x[1] + x[2] * x[2] + x[3] * x[3];
#pragma unroll
            for (int d2 = 1; d2 < 64; d2 <<= 1) ss += __shfl_xor(ss, d2);
            float scale = rsqrtf(ss * (1.f / DHEAD) + 1e-6f);
            const float* wp = isq ? qw : kw;
            float nx[4];
#pragma unroll
            for (int j = 0; j < 4; ++j)
                nx[j] = x[j] * scale * (1.f + wp[lane * 4 + j]);
            bf16x4 ov;
#pragma unroll
            for (int j = 0; j < 4; ++j) {
                float other = __shfl_xor(nx[j], 32);
                float rot = (lane < 32) ? -other : other;
                float v = nx[j] * cos4[j] + rot * sin4[j];
                if (isq) v *= 0.0625f;   // SCALE folded into q
                ov[j] = (__bf16)v;
            }
            __bf16* dst = isq ? (Qo + ((size_t)(b * NH + hh) * SEQ + s) * DHEAD)
                              : (Ko + ((size_t)(b * NKV + (hh - 8)) * SEQ + s) * DHEAD);
            *(bf16x4*)&dst[lane * 4] = ov;
        } else {
            int vh = hh - 12;
            const __bf16* src = QKV + (size_t)r * 4096 + 3072 + vh * DHEAD;
            bf16x4 xb = *(const bf16x4*)&src[lane * 4];
            __bf16* dst = Vo + ((size_t)(b * NKV + vh) * SEQ + s) * DHEAD;
            *(bf16x4*)&dst[lane * 4] = xb;
        }
    }
}

// ------------------ flash attention v9: in-block KV-split ------------------
// Block: (b,kh) x 32 q-rows, 8 waves = 2 heads x 2 qsub x 2 KV-halves.
// Half h owns kv[2h] (K) + kv[2h+1] (V), single-buffered (KVBLK=32).
// Loop: [stage own tile -> __syncthreads -> QK/SM/PV -> __syncthreads].
// Final: half1 writes (m,l,o) into the dead staging LDS; half0 merges the
// two online-softmax states and writes ctx. exp(-3e38 - m0) == 0 handles
// empty half1 ranges.
__global__ __launch_bounds__(512, 4)
void attn9(const __bf16* __restrict__ Q, const __bf16* __restrict__ Kb,
           const __bf16* __restrict__ Vb, __bf16* __restrict__ ctx) {
    const int bid = blockIdx.x;
    const int bk = bid & 7;            // XCD grouping: same (b,kh) -> same XCD
    const int qt = 63 - (bid >> 3);    // heavy blocks dispatch first
    const int b = bk >> 2, kh = bk & 3;
    const int q0 = qt * 32;
    const int tid = threadIdx.x;
    const int wave = tid >> 6, lane = tid & 63;
    const int lo = lane & 15, hi = lane >> 4;
    const int half = wave >> 2, hq = wave & 3;
    const int hsel = hq >> 1, qsub = hq & 1;
    const int h = kh * 2 + hsel;
    const int qbase = q0 + qsub * 16;
    const int q = qbase + lo;
    const int lt = tid & 255;          // local tid within half
    const int lw = hq;                 // local wave within half

    __shared__ __align__(16) __bf16 kv[4][32 * 256];   // 4 x 16 KB
    __shared__ float mlb[4][2][16];                    // merge scalars

    const __bf16* Qp = Q + ((size_t)(b * NH + h) * SEQ + qbase) * DHEAD;
    const __bf16* Kp = Kb + (size_t)(b * NKV + kh) * SEQ * DHEAD;
    const __bf16* Vp = Vb + (size_t)(b * NKV + kh) * SEQ * DHEAD;

    int koff[4], voff[4];
#pragma unroll
    for (int i = 0; i < 4; ++i) {
        int n = i * 256 + lt;                  // 16B slot index within half
        int r = n >> 5, c = n & 31;
        koff[i] = r * 256 + ((c ^ (r & 7)) << 3);
        int st = n >> 3, w = n & 7;
        int vk = (st & 7) * 4 + (w >> 1);
        int vd = (st >> 3) * 16 + (w & 1) * 8;
        voff[i] = vk * 256 + vd;
    }

    auto stage = [&](int c0) {                 // stage own half's K+V tile
        const __bf16* kg = Kp + (size_t)c0 * DHEAD;
        const __bf16* vg = Vp + (size_t)c0 * DHEAD;
        char* kd = (char*)&kv[2 * half][0] + lw * 1024;
        char* vd = (char*)&kv[2 * half + 1][0] + lw * 1024;
#pragma unroll
        for (int i = 0; i < 4; ++i) {
            gload_lds16(kg + koff[i], kd + i * 4096);
            gload_lds16(vg + voff[i], vd + i * 4096);
        }
    };

    bf16x8 qf[8];
#pragma unroll
    for (int dc = 0; dc < 8; ++dc)
        qf[dc] = *(const bf16x8*)(Qp + (size_t)lo * DHEAD + dc * 32 + hi * 8);

    f32x4 o[16] = {};
    float m = -3e38f, l = 0.f;

    int kstart = q0 - SWIN; if (kstart < 0) kstart = 0;
    const int nt = (q0 + 32 - kstart) >> 5;
    const int nh = (nt + 1) >> 1;              // half0: [0,nh), half1: [nh,nt)

    for (int i = 0; i < nh; ++i) {
        const int tt = half ? (nh + i) : i;
        const bool valid = half ? (tt < nt) : true;
        const int c0 = kstart + tt * 32;
        if (valid) stage(c0);
        __syncthreads();                       // drain + publish own half's tile

        if (valid) {
            // ---- QK^T (swapped): keys c0+hi*4+j (sc0) / +16 (sc1), q = lo
            f32x4 sc0 = {}, sc1 = {};
            const __bf16* kb0 = &kv[2 * half][0];
            __builtin_amdgcn_s_setprio(1);
#pragma unroll
            for (int dc = 0; dc < 8; ++dc) {
                int u = dc * 4 + hi;
                bf16x8 kfa = *(const bf16x8*)&kb0[lo * 256 + ((u ^ (lo & 7)) << 3)];
                bf16x8 kfb = *(const bf16x8*)&kb0[(16 + lo) * 256 + ((u ^ ((16 + lo) & 7)) << 3)];
                sc0 = __builtin_amdgcn_mfma_f32_16x16x32_bf16(kfa, qf[dc], sc0, 0, 0, 0);
                sc1 = __builtin_amdgcn_mfma_f32_16x16x32_bf16(kfb, qf[dc], sc1, 0, 0, 0);
            }
            __builtin_amdgcn_s_setprio(0);

            // ---- mask + lane-parallel online softmax (state keyed q = lo)
            float s8[8];
#pragma unroll
            for (int j = 0; j < 4; ++j) {
                int ka = c0 + hi * 4 + j;
                int kb2 = ka + 16;
                s8[j]     = (ka <= q && q - ka < SWIN) ? sc0[j] : -1e30f;
                s8[4 + j] = (kb2 <= q && q - kb2 < SWIN) ? sc1[j] : -1e30f;
            }
            float pm = s8[0];
#pragma unroll
            for (int i2 = 1; i2 < 8; ++i2) pm = fmaxf(pm, s8[i2]);
            pm = fmaxf(pm, __shfl_xor(pm, 16));
            pm = fmaxf(pm, __shfl_xor(pm, 32));
            if (__any(pm > m + 8.f)) {             // T13 defer-max
                float mn = fmaxf(m, pm);
                float corr = __expf(m - mn);
                l *= corr;
#pragma unroll
                for (int dt = 0; dt < 16; ++dt) o[dt] *= corr;
                m = mn;
            }
            float p8[8], ps = 0.f;
#pragma unroll
            for (int i2 = 0; i2 < 8; ++i2) {
                float e = __expf(s8[i2] - m);
                p8[i2] = (s8[i2] > -9e29f) ? e : 0.f;
                ps += p8[i2];
            }
            ps += __shfl_xor(ps, 16);
            ps += __shfl_xor(ps, 32);
            l += ps;

            bf16x8 paf;
#pragma unroll
            for (int i2 = 0; i2 < 8; ++i2) paf[i2] = (__bf16)p8[i2];

            // ---- PV: o[dt][j] = O^T[d = dt*16+hi*4+j][q = lo]
            const __bf16* vb0 = &kv[2 * half + 1][0];
#pragma unroll
            for (int dq = 0; dq < 4; ++dq) {
                bf16x4 t0[4], t1[4];
#pragma unroll
                for (int u = 0; u < 4; ++u) {
                    int dt = dq * 4 + u;
                    t0[u] = tr16(vb0 + (dt * 8 + hi) * 64 + lo * 4);       // k 0..3
                    t1[u] = tr16(vb0 + (dt * 8 + 4 + hi) * 64 + lo * 4);   // k 4..7
                }
                asm volatile("s_waitcnt lgkmcnt(0)" ::: "memory");
                __builtin_amdgcn_sched_barrier(0);
                __builtin_amdgcn_s_setprio(1);
#pragma unroll
                for (int u = 0; u < 4; ++u) {
                    bf16x8 vf;
#pragma unroll
                    for (int j = 0; j < 4; ++j) { vf[j] = t0[u][j]; vf[4 + j] = t1[u][j]; }
                    o[dq * 4 + u] = __builtin_amdgcn_mfma_f32_16x16x32_bf16(vf, paf, o[dq * 4 + u], 0, 0, 0);
                }
                __builtin_amdgcn_s_setprio(0);
            }
        }
        __syncthreads();                       // reads retired -> restage safe
    }

    // ---- merge the two halves' online-softmax states (staging LDS is dead)
    float* mbase = (float*)&kv[0][0] + hq * 4096;   // 16KB region per pair
    if (half == 1) {
#pragma unroll
        for (int dt = 0; dt < 16; ++dt)
            *(f32x4*)&mbase[lo * 256 + dt * 16 + hi * 4] = o[dt];
        if (hi == 0) { mlb[hq][0][lo] = m; mlb[hq][1][lo] = l; }
    }
    __syncthreads();
    if (half == 0) {
        float m1 = mlb[hq][0][lo], l1 = mlb[hq][1][lo];
        float ms = fmaxf(m, m1);
        float c0f = __expf(m - ms), c1f = __expf(m1 - ms);
        float lt2 = l * c0f + l1 * c1f;
        float invl = 1.0f / lt2;
        __bf16* cp = ctx + ((size_t)(b * SEQ + q)) * (NH * DHEAD) + h * DHEAD;
#pragma unroll
        for (int dt = 0; dt < 16; ++dt) {
            f32x4 v1 = *(const f32x4*)&mbase[lo * 256 + dt * 16 + hi * 4];
            bf16x4 w;
#pragma unroll
            for (int j = 0; j < 4; ++j)
                w[j] = (__bf16)((o[dt][j] * c0f + v1[j] * c1f) * invl);
            *(bf16x4*)&cp[dt * 16 + hi * 4] = w;
        }
    }
}

// ---------------------------------------------------------------------------
extern "C" void kernel_launch(void* const* d_in, const int* in_sizes, int n_in,
                              void* d_out, int out_size, void* d_ws, size_t ws_size,
                              hipStream_t stream) {
    const float* hs = (const float*)d_in[0];
    const float* Wq = (const float*)d_in[1];
    const float* Wk = (const float*)d_in[2];
    const float* Wv = (const float*)d_in[3];
    const float* Wo = (const float*)d_in[4];
    const float* qw = (const float*)d_in[5];
    const float* kw = (const float*)d_in[6];
    float* out = (float*)d_out;

    char* ws = (char*)d_ws;
    size_t off = 0;
    auto alloc = [&](size_t bytes) {
        char* p = ws + off;
        off += (bytes + 255) & ~(size_t)255;
        return p;
    };
    const int M = NB * SEQ;                       // 4096
    __bf16* hsB   = (__bf16*)alloc((size_t)M * DMODEL * 2);
    __bf16* WqkvB = (__bf16*)alloc((size_t)4096 * DMODEL * 2);
    __bf16* WoB   = (__bf16*)alloc((size_t)DMODEL * DMODEL * 2);
    __bf16* QKVb  = (__bf16*)alloc((size_t)M * 4096 * 2);
    __bf16* Qb    = (__bf16*)alloc((size_t)M * 2048 * 2);
    __bf16* Kbf   = (__bf16*)alloc((size_t)M * 1024 * 2);
    __bf16* Vbf   = (__bf16*)alloc((size_t)M * 1024 * 2);
    float*  cosT  = (float*) alloc((size_t)SEQ * 128 * 4);
    float*  sinT  = (float*) alloc((size_t)SEQ * 128 * 4);
    __bf16* ctxB  = QKVb;                         // reuse: QKV dead after norm_rope

    cvt_rope<<<21504, 256, 0, stream>>>(hs, Wq, Wk, Wv, Wo,
                                        hsB, WqkvB, WqkvB + (size_t)2048 * 2048,
                                        WqkvB + (size_t)3072 * 2048, WoB, cosT, sinT);

    // fused QKV projection: 256 blocks (16x16 tiles of 256), bf16 output
    gemm_bt8<1><<<256, 512, 0, stream>>>(hsB, WqkvB, QKVb, M, 4096, DMODEL, 16);

    norm_rope<<<M, 256, 0, stream>>>(QKVb, qw, kw, cosT, sinT, Qb, Kbf, Vbf);

    attn9<<<512, 512, 0, stream>>>(Qb, Kbf, Vbf, ctxB);

    // output projection: 256 blocks (16x16 tiles of 256x128)
    gemm_bt8n<<<256, 512, 0, stream>>>(ctxB, WoB, out, M, DMODEL, DMODEL, 16);
}

// Round 15
// 229.719 us; speedup vs baseline: 1.7877x; 1.7877x over previous
//
#include <hip/hip_runtime.h>
#include <hip/hip_bf16.h>

// ---------------------------------------------------------------------------
// Gemma sliding-window attention layer, MI355X round 15.
// attn9b = r14's in-block KV-split with the register catastrophe fixed:
// launch_bounds(512,2) (no forced 128-VGPR cap -> no scratch spills) and
// koff/voff recomputed in stage() (saves 8 VGPRs toward the 128 threshold).
// GEMMs / norm_rope / cvt frozen from round 10.
// ---------------------------------------------------------------------------

typedef __bf16 bf16x8 __attribute__((ext_vector_type(8)));
typedef __bf16 bf16x4 __attribute__((ext_vector_type(4)));
typedef float f32x4 __attribute__((ext_vector_type(4)));

#define NB 2
#define SEQ 2048
#define DMODEL 2048
#define NH 8
#define NKV 4
#define DHEAD 256
#define SWIN 1024

#define AS1 __attribute__((address_space(1)))
#define AS3 __attribute__((address_space(3)))

static __device__ __forceinline__ void gload_lds16(const void* g, void* l) {
    __builtin_amdgcn_global_load_lds((const AS1 void*)g, (AS3 void*)l, 16, 0, 0);
}

static __device__ __forceinline__ bf16x4 tr16(const __bf16* p) {
    bf16x4 r;
    asm volatile("ds_read_b64_tr_b16 %0, %1" : "=v"(r) : "v"((const AS3 __bf16*)p));
    return r;
}

// ------------------- merged f32->bf16 convert + RoPE table ------------------
__global__ void cvt_rope(const float* __restrict__ s0, const float* __restrict__ s1,
                         const float* __restrict__ s2, const float* __restrict__ s3,
                         const float* __restrict__ s4, __bf16* __restrict__ d0,
                         __bf16* __restrict__ d1, __bf16* __restrict__ d2,
                         __bf16* __restrict__ d3, __bf16* __restrict__ d4,
                         float* __restrict__ cosT, float* __restrict__ sinT) {
    if (blockIdx.x >= 20480) {
        int idx = (blockIdx.x - 20480) * 256 + threadIdx.x;   // < 262144
        int s = idx >> 7, i = idx & 127;
        float fr = (float)s * __expf(-(float)i * 0.0719557843f);  // ln(1e4)/128
        cosT[idx] = cosf(fr);
        sinT[idx] = sinf(fr);
        return;
    }
    int i = blockIdx.x * 256 + threadIdx.x;      // covers exactly 5242880
    const float* src; __bf16* dst;
    if (i < 2097152) { src = s0; dst = d0; }
    else if (i < 3145728) { i -= 2097152; src = s1; dst = d1; }
    else if (i < 3670016) { i -= 3145728; src = s2; dst = d2; }
    else if (i < 4194304) { i -= 3670016; src = s3; dst = d3; }
    else                  { i -= 4194304; src = s4; dst = d4; }
    f32x4 v = ((const f32x4*)src)[i];
    bf16x4 o;
#pragma unroll
    for (int j = 0; j < 4; ++j) o[j] = (__bf16)v[j];
    ((bf16x4*)dst)[i] = o;
}

// --------- GEMM 256x256, BK=64, 8-phase pipelined: C = A[M,K] * B[N,K]^T ---
template <int OUTBF16>
__global__ __launch_bounds__(512, 2)
void gemm_bt8(const __bf16* __restrict__ A, const __bf16* __restrict__ B,
              void* __restrict__ Cv, int M, int N, int K, int nbx) {
    __shared__ __align__(16) __bf16 sA[2][256 * 64];   // 64 KB
    __shared__ __align__(16) __bf16 sB[2][256 * 64];   // 64 KB
    const int tid = threadIdx.x;
    const int wave = tid >> 6, lane = tid & 63;
    const int lo = lane & 15, hi = lane >> 4;
    const int wm = wave >> 2, wn = wave & 3;
    const int qq = (int)gridDim.x >> 3;
    const int swz = ((int)blockIdx.x & 7) * qq + ((int)blockIdx.x >> 3);
    const int bx = swz % nbx, by = swz / nbx;
    const int brow = by * 256, bcol = bx * 256;
    const int xr = lo & 7;

    int aoff[4];
#pragma unroll
    for (int i = 0; i < 4; ++i) {
        int n = i * 512 + tid, r = n >> 3, s = n & 7;
        aoff[i] = r * K + ((s ^ (r & 7)) << 3);   // pre-swizzled global source
    }
    const __bf16* Ab = A + (size_t)brow * K;
    const __bf16* Bb = B + (size_t)bcol * K;

    auto stgA = [&](int bsel, int kt, int h) {
        const __bf16* ga = Ab + kt * 64;
#pragma unroll
        for (int ii = 0; ii < 2; ++ii) {
            int i = h + ii * 2;
            gload_lds16(ga + aoff[i], (char*)&sA[bsel][0] + (i * 512 + wave * 64) * 16);
        }
    };
    auto stgB = [&](int bsel, int kt, int h) {
        const __bf16* gb = Bb + kt * 64;
#pragma unroll
        for (int i = 2 * h; i < 2 * h + 2; ++i)
            gload_lds16(gb + aoff[i], (char*)&sB[bsel][0] + (i * 512 + wave * 64) * 16);
    };

    f32x4 acc[8][4] = {};
    const int nt = K >> 6;

    stgA(0, 0, 0); stgA(0, 0, 1); stgB(0, 0, 0); stgB(0, 0, 1);
    stgA(1, 1, 0); stgA(1, 1, 1); stgB(1, 1, 0); stgB(1, 1, 1);
    asm volatile("s_waitcnt vmcnt(8)" ::: "memory");   // tile0 landed
    __builtin_amdgcn_s_barrier();

    for (int t = 0; t < nt; ++t) {
        const int buf = t & 1;
        const bool pre = (t + 2 < nt);
        const __bf16* sa = &sA[buf][0];
        const __bf16* sb = &sB[buf][0];
        bf16x8 af[8], b0[4], b1[4];
        // ---- g0: ds_read A rows wm*128+0..63 (slots {0,2}) + B-nh0; MFMA Q0
#pragma unroll
        for (int m = 0; m < 4; ++m)
#pragma unroll
            for (int ks = 0; ks < 2; ++ks)
                af[m * 2 + ks] = *(const bf16x8*)&sa[(wm * 128 + m * 16 + lo) * 64 + (((ks * 4 + hi) ^ xr) << 3)];
#pragma unroll
        for (int n = 0; n < 2; ++n)
#pragma unroll
            for (int ks = 0; ks < 2; ++ks)
                b0[n * 2 + ks] = *(const bf16x8*)&sb[(wn * 64 + n * 16 + lo) * 64 + (((ks * 4 + hi) ^ xr) << 3)];
        __builtin_amdgcn_sched_barrier(0);
        __builtin_amdgcn_s_barrier();
        __builtin_amdgcn_s_setprio(1);
#pragma unroll
        for (int m = 0; m < 4; ++m)
#pragma unroll
            for (int n = 0; n < 2; ++n)
#pragma unroll
                for (int ks = 0; ks < 2; ++ks)
                    acc[m][n] = __builtin_amdgcn_mfma_f32_16x16x32_bf16(af[m * 2 + ks], b0[n * 2 + ks], acc[m][n], 0, 0, 0);
        __builtin_amdgcn_s_setprio(0);
        __builtin_amdgcn_sched_barrier(0);
        __builtin_amdgcn_s_barrier();
        // ---- g1: ds_read B-nh1; stage A-set0(t+2); MFMA Q1
#pragma unroll
        for (int n = 0; n < 2; ++n)
#pragma unroll
            for (int ks = 0; ks < 2; ++ks)
                b1[n * 2 + ks] = *(const bf16x8*)&sb[(wn * 64 + (n + 2) * 16 + lo) * 64 + (((ks * 4 + hi) ^ xr) << 3)];
        if (pre) stgA(buf, t + 2, 0);
        __builtin_amdgcn_sched_barrier(0);
        __builtin_amdgcn_s_barrier();
        __builtin_amdgcn_s_setprio(1);
#pragma unroll
        for (int m = 0; m < 4; ++m)
#pragma unroll
            for (int n = 0; n < 2; ++n)
#pragma unroll
                for (int ks = 0; ks < 2; ++ks)
                    acc[m][n + 2] = __builtin_amdgcn_mfma_f32_16x16x32_bf16(af[m * 2 + ks], b1[n * 2 + ks], acc[m][n + 2], 0, 0, 0);
        __builtin_amdgcn_s_setprio(0);
        __builtin_amdgcn_sched_barrier(0);
        __builtin_amdgcn_s_barrier();
        // ---- g2: ds_read A rows wm*128+64..127 (slots {1,3}); stage B{2,3}(t+2); MFMA Q2
#pragma unroll
        for (int m = 0; m < 4; ++m)
#pragma unroll
            for (int ks = 0; ks < 2; ++ks)
                af[m * 2 + ks] = *(const bf16x8*)&sa[(wm * 128 + (m + 4) * 16 + lo) * 64 + (((ks * 4 + hi) ^ xr) << 3)];
        if (pre) stgB(buf, t + 2, 1);
        __builtin_amdgcn_sched_barrier(0);
        __builtin_amdgcn_s_barrier();
        __builtin_amdgcn_s_setprio(1);
#pragma unroll
        for (int m = 0; m < 4; ++m)
#pragma unroll
            for (int n = 0; n < 2; ++n)
#pragma unroll
                for (int ks = 0; ks < 2; ++ks)
                    acc[m + 4][n + 2] = __builtin_amdgcn_mfma_f32_16x16x32_bf16(af[m * 2 + ks], b1[n * 2 + ks], acc[m + 4][n + 2], 0, 0, 0);
        __builtin_amdgcn_s_setprio(0);
        __builtin_amdgcn_sched_barrier(0);
        __builtin_amdgcn_s_barrier();
        // ---- g3: stage A-set1{1,3}+B{0,1}(t+2); MFMA Q3; vmcnt(8)
        if (pre) { stgA(buf, t + 2, 1); stgB(buf, t + 2, 0); }
        __builtin_amdgcn_sched_barrier(0);
        __builtin_amdgcn_s_setprio(1);
#pragma unroll
        for (int m = 0; m < 4; ++m)
#pragma unroll
            for (int n = 0; n < 2; ++n)
#pragma unroll
                for (int ks = 0; ks < 2; ++ks)
                    acc[m + 4][n] = __builtin_amdgcn_mfma_f32_16x16x32_bf16(af[m * 2 + ks], b0[n * 2 + ks], acc[m + 4][n], 0, 0, 0);
        __builtin_amdgcn_s_setprio(0);
        if (pre) asm volatile("s_waitcnt vmcnt(8)" ::: "memory");
        else     asm volatile("s_waitcnt vmcnt(0)" ::: "memory");
        __builtin_amdgcn_sched_barrier(0);
        __builtin_amdgcn_s_barrier();
    }

#pragma unroll
    for (int m = 0; m < 8; ++m) {
        int row = brow + wm * 128 + m * 16 + hi * 4;
#pragma unroll
        for (int n = 0; n < 4; ++n) {
            int col = bcol + wn * 64 + n * 16 + lo;
            if constexpr (OUTBF16) {
                __bf16* cp = (__bf16*)Cv + (size_t)row * N + col;
#pragma unroll
                for (int j = 0; j < 4; ++j)
                    cp[(size_t)j * N] = (__bf16)acc[m][n][j];
            } else {
                float* cp = (float*)Cv + (size_t)row * N + col;
#pragma unroll
                for (int j = 0; j < 4; ++j)
                    cp[(size_t)j * N] = acc[m][n][j];
            }
        }
    }
}

// --------- GEMM 256x128, BK=64, out-proj (full machine, frozen) ------------
__global__ __launch_bounds__(512, 2)
void gemm_bt8n(const __bf16* __restrict__ A, const __bf16* __restrict__ B,
               float* __restrict__ C, int M, int N, int K, int nbx) {
    __shared__ __align__(16) __bf16 sA[2][256 * 64];   // 64 KB
    __shared__ __align__(16) __bf16 sB[2][128 * 64];   // 32 KB
    const int tid = threadIdx.x;
    const int wave = tid >> 6, lane = tid & 63;
    const int lo = lane & 15, hi = lane >> 4;
    const int wm = wave >> 1, wn = wave & 1;
    const int qq = (int)gridDim.x >> 3;
    const int swz = ((int)blockIdx.x & 7) * qq + ((int)blockIdx.x >> 3);
    const int bx = swz % nbx, by = swz / nbx;
    const int brow = by * 256, bcol = bx * 128;
    const int xr = lo & 7;

    int aoff[4], boff[2];
#pragma unroll
    for (int i = 0; i < 4; ++i) {
        int n = i * 512 + tid, r = n >> 3, s = n & 7;
        aoff[i] = r * K + ((s ^ (r & 7)) << 3);
    }
#pragma unroll
    for (int i = 0; i < 2; ++i) {
        int n = i * 512 + tid, r = n >> 3, s = n & 7;
        boff[i] = r * K + ((s ^ (r & 7)) << 3);
    }
    const __bf16* Ab = A + (size_t)brow * K;
    const __bf16* Bb = B + (size_t)bcol * K;

    auto stgAall = [&](int bsel, int kt) {
        const __bf16* ga = Ab + kt * 64;
#pragma unroll
        for (int i = 0; i < 4; ++i)
            gload_lds16(ga + aoff[i], (char*)&sA[bsel][0] + (i * 512 + wave * 64) * 16);
    };
    auto stgBall = [&](int bsel, int kt) {
        const __bf16* gb = Bb + kt * 64;
#pragma unroll
        for (int i = 0; i < 2; ++i)
            gload_lds16(gb + boff[i], (char*)&sB[bsel][0] + (i * 512 + wave * 64) * 16);
    };

    f32x4 acc[4][4] = {};
    const int nt = K >> 6;

    stgAall(0, 0); stgBall(0, 0);      // 6 loads (tile0)
    stgAall(1, 1); stgBall(1, 1);      // 6 loads (tile1)
    asm volatile("s_waitcnt vmcnt(6)" ::: "memory");   // tile0 landed
    __builtin_amdgcn_s_barrier();

    for (int t = 0; t < nt; ++t) {
        const int buf = t & 1;
        const bool pre = (t + 2 < nt);
        const __bf16* sa = &sA[buf][0];
        const __bf16* sb = &sB[buf][0];
        bf16x8 af[4], b0[4], b1[4];
        // ---- g0: ds_read A m01 + B n01; MFMA Q0
#pragma unroll
        for (int m = 0; m < 2; ++m)
#pragma unroll
            for (int ks = 0; ks < 2; ++ks)
                af[m * 2 + ks] = *(const bf16x8*)&sa[(wm * 64 + m * 16 + lo) * 64 + (((ks * 4 + hi) ^ xr) << 3)];
#pragma unroll
        for (int n = 0; n < 2; ++n)
#pragma unroll
            for (int ks = 0; ks < 2; ++ks)
                b0[n * 2 + ks] = *(const bf16x8*)&sb[(wn * 64 + n * 16 + lo) * 64 + (((ks * 4 + hi) ^ xr) << 3)];
        __builtin_amdgcn_sched_barrier(0);
        __builtin_amdgcn_s_barrier();
        __builtin_amdgcn_s_setprio(1);
#pragma unroll
        for (int m = 0; m < 2; ++m)
#pragma unroll
            for (int n = 0; n < 2; ++n)
#pragma unroll
                for (int ks = 0; ks < 2; ++ks)
                    acc[m][n] = __builtin_amdgcn_mfma_f32_16x16x32_bf16(af[m * 2 + ks], b0[n * 2 + ks], acc[m][n], 0, 0, 0);
        __builtin_amdgcn_s_setprio(0);
        __builtin_amdgcn_sched_barrier(0);
        __builtin_amdgcn_s_barrier();
        // ---- g1: ds_read B n23; MFMA Q1
#pragma unroll
        for (int n = 0; n < 2; ++n)
#pragma unroll
            for (int ks = 0; ks < 2; ++ks)
                b1[n * 2 + ks] = *(const bf16x8*)&sb[(wn * 64 + (n + 2) * 16 + lo) * 64 + (((ks * 4 + hi) ^ xr) << 3)];
        __builtin_amdgcn_sched_barrier(0);
        __builtin_amdgcn_s_barrier();
        __builtin_amdgcn_s_setprio(1);
#pragma unroll
        for (int m = 0; m < 2; ++m)
#pragma unroll
            for (int n = 0; n < 2; ++n)
#pragma unroll
                for (int ks = 0; ks < 2; ++ks)
                    acc[m][n + 2] = __builtin_amdgcn_mfma_f32_16x16x32_bf16(af[m * 2 + ks], b1[n * 2 + ks], acc[m][n + 2], 0, 0, 0);
        __builtin_amdgcn_s_setprio(0);
        __builtin_amdgcn_sched_barrier(0);
        __builtin_amdgcn_s_barrier();
        // ---- g2: ds_read A m23; stage B(t+2); MFMA Q2
#pragma unroll
        for (int m = 0; m < 2; ++m)
#pragma unroll
            for (int ks = 0; ks < 2; ++ks)
                af[m * 2 + ks] = *(const bf16x8*)&sa[(wm * 64 + (m + 2) * 16 + lo) * 64 + (((ks * 4 + hi) ^ xr) << 3)];
        if (pre) stgBall(buf, t + 2);
        __builtin_amdgcn_sched_barrier(0);
        __builtin_amdgcn_s_barrier();
        __builtin_amdgcn_s_setprio(1);
#pragma unroll
        for (int m = 0; m < 2; ++m)
#pragma unroll
            for (int n = 0; n < 2; ++n)
#pragma unroll
                for (int ks = 0; ks < 2; ++ks)
                    acc[m + 2][n + 2] = __builtin_amdgcn_mfma_f32_16x16x32_bf16(af[m * 2 + ks], b1[n * 2 + ks], acc[m + 2][n + 2], 0, 0, 0);
        __builtin_amdgcn_s_setprio(0);
        __builtin_amdgcn_sched_barrier(0);
        __builtin_amdgcn_s_barrier();
        // ---- g3: stage A(t+2); MFMA Q3; vmcnt(6)
        if (pre) stgAall(buf, t + 2);
        __builtin_amdgcn_sched_barrier(0);
        __builtin_amdgcn_s_setprio(1);
#pragma unroll
        for (int m = 0; m < 2; ++m)
#pragma unroll
            for (int n = 0; n < 2; ++n)
#pragma unroll
                for (int ks = 0; ks < 2; ++ks)
                    acc[m + 2][n] = __builtin_amdgcn_mfma_f32_16x16x32_bf16(af[m * 2 + ks], b0[n * 2 + ks], acc[m + 2][n], 0, 0, 0);
        __builtin_amdgcn_s_setprio(0);
        if (pre) asm volatile("s_waitcnt vmcnt(6)" ::: "memory");
        else     asm volatile("s_waitcnt vmcnt(0)" ::: "memory");
        __builtin_amdgcn_sched_barrier(0);
        __builtin_amdgcn_s_barrier();
    }

#pragma unroll
    for (int m = 0; m < 4; ++m) {
        int row = brow + wm * 64 + m * 16 + hi * 4;
#pragma unroll
        for (int n = 0; n < 4; ++n) {
            float* cp = C + (size_t)row * N + bcol + wn * 64 + n * 16 + lo;
#pragma unroll
            for (int j = 0; j < 4; ++j)
                cp[(size_t)j * N] = acc[m][n][j];
        }
    }
}

// ---------- RMSNorm + RoPE (q,k) + V copy, from QKV bf16 (frozen) ----------
__global__ __launch_bounds__(256)
void norm_rope(const __bf16* __restrict__ QKV, const float* __restrict__ qw,
               const float* __restrict__ kw, const float* __restrict__ cosT,
               const float* __restrict__ sinT, __bf16* __restrict__ Qo,
               __bf16* __restrict__ Ko, __bf16* __restrict__ Vo) {
    const int r = blockIdx.x;            // b*S + s
    const int b = r >> 11, s = r & (SEQ - 1);
    const int wave = threadIdx.x >> 6, lane = threadIdx.x & 63;
    f32x4 cos4 = *(const f32x4*)&cosT[s * 128 + (lane & 31) * 4];
    f32x4 sin4 = *(const f32x4*)&sinT[s * 128 + (lane & 31) * 4];
#pragma unroll
    for (int ii = 0; ii < 4; ++ii) {
        int hh = wave + ii * 4;          // 0..15
        if (hh < 12) {
            bool isq = hh < 8;
            int col0 = isq ? hh * DHEAD : DMODEL + (hh - 8) * DHEAD;
            const __bf16* src = QKV + (size_t)r * 4096 + col0;
            bf16x4 xb = *(const bf16x4*)&src[lane * 4];
            float x[4];
#pragma unroll
            for (int j = 0; j < 4; ++j) x[j] = (float)xb[j];
            float ss = x[0] * x[0] + x[1] * x[1] + x[2] * x[2] + x[3] * x[3];
#pragma unroll
            for (int d2 = 1; d2 < 64; d2 <<= 1) ss += __shfl_xor(ss, d2);
            float scale = rsqrtf(ss * (1.f / DHEAD) + 1e-6f);
            const float* wp = isq ? qw : kw;
            float nx[4];
#pragma unroll
            for (int j = 0; j < 4; ++j)
                nx[j] = x[j] * scale * (1.f + wp[lane * 4 + j]);
            bf16x4 ov;
#pragma unroll
            for (int j = 0; j < 4; ++j) {
                float other = __shfl_xor(nx[j], 32);
                float rot = (lane < 32) ? -other : other;
                float v = nx[j] * cos4[j] + rot * sin4[j];
                if (isq) v *= 0.0625f;   // SCALE folded into q
                ov[j] = (__bf16)v;
            }
            __bf16* dst = isq ? (Qo + ((size_t)(b * NH + hh) * SEQ + s) * DHEAD)
                              : (Ko + ((size_t)(b * NKV + (hh - 8)) * SEQ + s) * DHEAD);
            *(bf16x4*)&dst[lane * 4] = ov;
        } else {
            int vh = hh - 12;
            const __bf16* src = QKV + (size_t)r * 4096 + 3072 + vh * DHEAD;
            bf16x4 xb = *(const bf16x4*)&src[lane * 4];
            __bf16* dst = Vo + ((size_t)(b * NKV + vh) * SEQ + s) * DHEAD;
            *(bf16x4*)&dst[lane * 4] = xb;
        }
    }
}

// ------------------ flash attention v9b: in-block KV-split -----------------
// Block: (b,kh) x 32 q-rows, 8 waves = 2 heads x 2 qsub x 2 KV-halves.
// launch_bounds(512,2): VGPR cap 256 -> no spills (r14 lesson). If the
// allocator lands <=128 VGPR, HW runs 2 blocks/CU = 16 waves/CU.
__global__ __launch_bounds__(512, 2)
void attn9(const __bf16* __restrict__ Q, const __bf16* __restrict__ Kb,
           const __bf16* __restrict__ Vb, __bf16* __restrict__ ctx) {
    const int bid = blockIdx.x;
    const int bk = bid & 7;            // XCD grouping: same (b,kh) -> same XCD
    const int qt = 63 - (bid >> 3);    // heavy blocks dispatch first
    const int b = bk >> 2, kh = bk & 3;
    const int q0 = qt * 32;
    const int tid = threadIdx.x;
    const int wave = tid >> 6, lane = tid & 63;
    const int lo = lane & 15, hi = lane >> 4;
    const int half = wave >> 2, hq = wave & 3;
    const int hsel = hq >> 1, qsub = hq & 1;
    const int h = kh * 2 + hsel;
    const int qbase = q0 + qsub * 16;
    const int q = qbase + lo;
    const int lt = tid & 255;          // local tid within half
    const int lw = hq;                 // local wave within half

    __shared__ __align__(16) __bf16 kv[4][32 * 256];   // 4 x 16 KB
    __shared__ float mlb[4][2][16];                    // merge scalars

    const __bf16* Qp = Q + ((size_t)(b * NH + h) * SEQ + qbase) * DHEAD;
    const __bf16* Kp = Kb + (size_t)(b * NKV + kh) * SEQ * DHEAD;
    const __bf16* Vp = Vb + (size_t)(b * NKV + kh) * SEQ * DHEAD;

    // offsets recomputed per call (saves 8 VGPRs vs cached arrays)
    auto stage = [&](int c0) {                 // stage own half's K+V tile
        const __bf16* kg = Kp + (size_t)c0 * DHEAD;
        const __bf16* vg = Vp + (size_t)c0 * DHEAD;
        char* kd = (char*)&kv[2 * half][0] + lw * 1024;
        char* vd = (char*)&kv[2 * half + 1][0] + lw * 1024;
#pragma unroll
        for (int i = 0; i < 4; ++i) {
            int n = i * 256 + lt;              // 16B slot index within half
            int r = n >> 5, c = n & 31;
            int ko = r * 256 + ((c ^ (r & 7)) << 3);
            int st = n >> 3, w = n & 7;
            int vk = (st & 7) * 4 + (w >> 1);
            int vd2 = (st >> 3) * 16 + (w & 1) * 8;
            gload_lds16(kg + ko, kd + i * 4096);
            gload_lds16(vg + vk * 256 + vd2, vd + i * 4096);
        }
    };

    bf16x8 qf[8];
#pragma unroll
    for (int dc = 0; dc < 8; ++dc)
        qf[dc] = *(const bf16x8*)(Qp + (size_t)lo * DHEAD + dc * 32 + hi * 8);

    f32x4 o[16] = {};
    float m = -3e38f, l = 0.f;

    int kstart = q0 - SWIN; if (kstart < 0) kstart = 0;
    const int nt = (q0 + 32 - kstart) >> 5;
    const int nh = (nt + 1) >> 1;              // half0: [0,nh), half1: [nh,nt)

    for (int i = 0; i < nh; ++i) {
        const int tt = half ? (nh + i) : i;
        const bool valid = half ? (tt < nt) : true;
        const int c0 = kstart + tt * 32;
        if (valid) stage(c0);
        __syncthreads();                       // drain + publish own half's tile

        if (valid) {
            // ---- QK^T (swapped): keys c0+hi*4+j (sc0) / +16 (sc1), q = lo
            f32x4 sc0 = {}, sc1 = {};
            const __bf16* kb0 = &kv[2 * half][0];
            __builtin_amdgcn_s_setprio(1);
#pragma unroll
            for (int dc = 0; dc < 8; ++dc) {
                int u = dc * 4 + hi;
                bf16x8 kfa = *(const bf16x8*)&kb0[lo * 256 + ((u ^ (lo & 7)) << 3)];
                bf16x8 kfb = *(const bf16x8*)&kb0[(16 + lo) * 256 + ((u ^ ((16 + lo) & 7)) << 3)];
                sc0 = __builtin_amdgcn_mfma_f32_16x16x32_bf16(kfa, qf[dc], sc0, 0, 0, 0);
                sc1 = __builtin_amdgcn_mfma_f32_16x16x32_bf16(kfb, qf[dc], sc1, 0, 0, 0);
            }
            __builtin_amdgcn_s_setprio(0);

            // ---- mask + lane-parallel online softmax (state keyed q = lo)
            float s8[8];
#pragma unroll
            for (int j = 0; j < 4; ++j) {
                int ka = c0 + hi * 4 + j;
                int kb2 = ka + 16;
                s8[j]     = (ka <= q && q - ka < SWIN) ? sc0[j] : -1e30f;
                s8[4 + j] = (kb2 <= q && q - kb2 < SWIN) ? sc1[j] : -1e30f;
            }
            float pm = s8[0];
#pragma unroll
            for (int i2 = 1; i2 < 8; ++i2) pm = fmaxf(pm, s8[i2]);
            pm = fmaxf(pm, __shfl_xor(pm, 16));
            pm = fmaxf(pm, __shfl_xor(pm, 32));
            if (__any(pm > m + 8.f)) {             // T13 defer-max
                float mn = fmaxf(m, pm);
                float corr = __expf(m - mn);
                l *= corr;
#pragma unroll
                for (int dt = 0; dt < 16; ++dt) o[dt] *= corr;
                m = mn;
            }
            float p8[8], ps = 0.f;
#pragma unroll
            for (int i2 = 0; i2 < 8; ++i2) {
                float e = __expf(s8[i2] - m);
                p8[i2] = (s8[i2] > -9e29f) ? e : 0.f;
                ps += p8[i2];
            }
            ps += __shfl_xor(ps, 16);
            ps += __shfl_xor(ps, 32);
            l += ps;

            bf16x8 paf;
#pragma unroll
            for (int i2 = 0; i2 < 8; ++i2) paf[i2] = (__bf16)p8[i2];

            // ---- PV: o[dt][j] = O^T[d = dt*16+hi*4+j][q = lo]
            const __bf16* vb0 = &kv[2 * half + 1][0];
#pragma unroll
            for (int dq = 0; dq < 4; ++dq) {
                bf16x4 t0[4], t1[4];
#pragma unroll
                for (int u = 0; u < 4; ++u) {
                    int dt = dq * 4 + u;
                    t0[u] = tr16(vb0 + (dt * 8 + hi) * 64 + lo * 4);       // k 0..3
                    t1[u] = tr16(vb0 + (dt * 8 + 4 + hi) * 64 + lo * 4);   // k 4..7
                }
                asm volatile("s_waitcnt lgkmcnt(0)" ::: "memory");
                __builtin_amdgcn_sched_barrier(0);
                __builtin_amdgcn_s_setprio(1);
#pragma unroll
                for (int u = 0; u < 4; ++u) {
                    bf16x8 vf;
#pragma unroll
                    for (int j = 0; j < 4; ++j) { vf[j] = t0[u][j]; vf[4 + j] = t1[u][j]; }
                    o[dq * 4 + u] = __builtin_amdgcn_mfma_f32_16x16x32_bf16(vf, paf, o[dq * 4 + u], 0, 0, 0);
                }
                __builtin_amdgcn_s_setprio(0);
            }
        }
        __syncthreads();                       // reads retired -> restage safe
    }

    // ---- merge the two halves' online-softmax states (staging LDS is dead)
    float* mbase = (float*)&kv[0][0] + hq * 4096;   // 16KB region per pair
    if (half == 1) {
#pragma unroll
        for (int dt = 0; dt < 16; ++dt)
            *(f32x4*)&mbase[lo * 256 + dt * 16 + hi * 4] = o[dt];
        if (hi == 0) { mlb[hq][0][lo] = m; mlb[hq][1][lo] = l; }
    }
    __syncthreads();
    if (half == 0) {
        float m1 = mlb[hq][0][lo], l1 = mlb[hq][1][lo];
        float ms = fmaxf(m, m1);
        float c0f = __expf(m - ms), c1f = __expf(m1 - ms);
        float lt2 = l * c0f + l1 * c1f;
        float invl = 1.0f / lt2;
        __bf16* cp = ctx + ((size_t)(b * SEQ + q)) * (NH * DHEAD) + h * DHEAD;
#pragma unroll
        for (int dt = 0; dt < 16; ++dt) {
            f32x4 v1 = *(const f32x4*)&mbase[lo * 256 + dt * 16 + hi * 4];
            bf16x4 w;
#pragma unroll
            for (int j = 0; j < 4; ++j)
                w[j] = (__bf16)((o[dt][j] * c0f + v1[j] * c1f) * invl);
            *(bf16x4*)&cp[dt * 16 + hi * 4] = w;
        }
    }
}

// ---------------------------------------------------------------------------
extern "C" void kernel_launch(void* const* d_in, const int* in_sizes, int n_in,
                              void* d_out, int out_size, void* d_ws, size_t ws_size,
                              hipStream_t stream) {
    const float* hs = (const float*)d_in[0];
    const float* Wq = (const float*)d_in[1];
    const float* Wk = (const float*)d_in[2];
    const float* Wv = (const float*)d_in[3];
    const float* Wo = (const float*)d_in[4];
    const float* qw = (const float*)d_in[5];
    const float* kw = (const float*)d_in[6];
    float* out = (float*)d_out;

    char* ws = (char*)d_ws;
    size_t off = 0;
    auto alloc = [&](size_t bytes) {
        char* p = ws + off;
        off += (bytes + 255) & ~(size_t)255;
        return p;
    };
    const int M = NB * SEQ;                       // 4096
    __bf16* hsB   = (__bf16*)alloc((size_t)M * DMODEL * 2);
    __bf16* WqkvB = (__bf16*)alloc((size_t)4096 * DMODEL * 2);
    __bf16* WoB   = (__bf16*)alloc((size_t)DMODEL * DMODEL * 2);
    __bf16* QKVb  = (__bf16*)alloc((size_t)M * 4096 * 2);
    __bf16* Qb    = (__bf16*)alloc((size_t)M * 2048 * 2);
    __bf16* Kbf   = (__bf16*)alloc((size_t)M * 1024 * 2);
    __bf16* Vbf   = (__bf16*)alloc((size_t)M * 1024 * 2);
    float*  cosT  = (float*) alloc((size_t)SEQ * 128 * 4);
    float*  sinT  = (float*) alloc((size_t)SEQ * 128 * 4);
    __bf16* ctxB  = QKVb;                         // reuse: QKV dead after norm_rope

    cvt_rope<<<21504, 256, 0, stream>>>(hs, Wq, Wk, Wv, Wo,
                                        hsB, WqkvB, WqkvB + (size_t)2048 * 2048,
                                        WqkvB + (size_t)3072 * 2048, WoB, cosT, sinT);

    // fused QKV projection: 256 blocks (16x16 tiles of 256), bf16 output
    gemm_bt8<1><<<256, 512, 0, stream>>>(hsB, WqkvB, QKVb, M, 4096, DMODEL, 16);

    norm_rope<<<M, 256, 0, stream>>>(QKVb, qw, kw, cosT, sinT, Qb, Kbf, Vbf);

    attn9<<<512, 512, 0, stream>>>(Qb, Kbf, Vbf, ctxB);

    // output projection: 256 blocks (16x16 tiles of 256x128)
    gemm_bt8n<<<256, 512, 0, stream>>>(ctxB, WoB, out, M, DMODEL, DMODEL, 16);
}

// Round 16
// 204.752 us; speedup vs baseline: 2.0057x; 1.1219x over previous
//
#include <hip/hip_runtime.h>
#include <hip/hip_bf16.h>

// ---------------------------------------------------------------------------
// Gemma sliding-window attention layer, MI355X round 16.
// Verbatim revert to the round-13 optimum (204.7 us): attn8 (counted vmcnt,
// 48KB LDS, flat-issue PV with lgkmcnt 15/15/8/0), 256x256 8-phase QKV GEMM
// with bf16 epilogue, 256x128 out-proj, fused cvt+rope, bf16 norm_rope.
// r14/r15's KV-split abandoned: occupancy is grid-limited (2 blocks/CU), and
// the split's full-drain loop + doubled bank conflicts cost 21 us vs attn8.
// ---------------------------------------------------------------------------

typedef __bf16 bf16x8 __attribute__((ext_vector_type(8)));
typedef __bf16 bf16x4 __attribute__((ext_vector_type(4)));
typedef float f32x4 __attribute__((ext_vector_type(4)));

#define NB 2
#define SEQ 2048
#define DMODEL 2048
#define NH 8
#define NKV 4
#define DHEAD 256
#define SWIN 1024

#define AS1 __attribute__((address_space(1)))
#define AS3 __attribute__((address_space(3)))

static __device__ __forceinline__ void gload_lds16(const void* g, void* l) {
    __builtin_amdgcn_global_load_lds((const AS1 void*)g, (AS3 void*)l, 16, 0, 0);
}

static __device__ __forceinline__ bf16x4 tr16(const __bf16* p) {
    bf16x4 r;
    asm volatile("ds_read_b64_tr_b16 %0, %1" : "=v"(r) : "v"((const AS3 __bf16*)p));
    return r;
}

// ------------------- merged f32->bf16 convert + RoPE table ------------------
__global__ void cvt_rope(const float* __restrict__ s0, const float* __restrict__ s1,
                         const float* __restrict__ s2, const float* __restrict__ s3,
                         const float* __restrict__ s4, __bf16* __restrict__ d0,
                         __bf16* __restrict__ d1, __bf16* __restrict__ d2,
                         __bf16* __restrict__ d3, __bf16* __restrict__ d4,
                         float* __restrict__ cosT, float* __restrict__ sinT) {
    if (blockIdx.x >= 20480) {
        int idx = (blockIdx.x - 20480) * 256 + threadIdx.x;   // < 262144
        int s = idx >> 7, i = idx & 127;
        float fr = (float)s * __expf(-(float)i * 0.0719557843f);  // ln(1e4)/128
        cosT[idx] = cosf(fr);
        sinT[idx] = sinf(fr);
        return;
    }
    int i = blockIdx.x * 256 + threadIdx.x;      // covers exactly 5242880
    const float* src; __bf16* dst;
    if (i < 2097152) { src = s0; dst = d0; }
    else if (i < 3145728) { i -= 2097152; src = s1; dst = d1; }
    else if (i < 3670016) { i -= 3145728; src = s2; dst = d2; }
    else if (i < 4194304) { i -= 3670016; src = s3; dst = d3; }
    else                  { i -= 4194304; src = s4; dst = d4; }
    f32x4 v = ((const f32x4*)src)[i];
    bf16x4 o;
#pragma unroll
    for (int j = 0; j < 4; ++j) o[j] = (__bf16)v[j];
    ((bf16x4*)dst)[i] = o;
}

// --------- GEMM 256x256, BK=64, 8-phase pipelined: C = A[M,K] * B[N,K]^T ---
template <int OUTBF16>
__global__ __launch_bounds__(512, 2)
void gemm_bt8(const __bf16* __restrict__ A, const __bf16* __restrict__ B,
              void* __restrict__ Cv, int M, int N, int K, int nbx) {
    __shared__ __align__(16) __bf16 sA[2][256 * 64];   // 64 KB
    __shared__ __align__(16) __bf16 sB[2][256 * 64];   // 64 KB
    const int tid = threadIdx.x;
    const int wave = tid >> 6, lane = tid & 63;
    const int lo = lane & 15, hi = lane >> 4;
    const int wm = wave >> 2, wn = wave & 3;
    const int qq = (int)gridDim.x >> 3;
    const int swz = ((int)blockIdx.x & 7) * qq + ((int)blockIdx.x >> 3);
    const int bx = swz % nbx, by = swz / nbx;
    const int brow = by * 256, bcol = bx * 256;
    const int xr = lo & 7;

    int aoff[4];
#pragma unroll
    for (int i = 0; i < 4; ++i) {
        int n = i * 512 + tid, r = n >> 3, s = n & 7;
        aoff[i] = r * K + ((s ^ (r & 7)) << 3);   // pre-swizzled global source
    }
    const __bf16* Ab = A + (size_t)brow * K;
    const __bf16* Bb = B + (size_t)bcol * K;

    auto stgA = [&](int bsel, int kt, int h) {
        const __bf16* ga = Ab + kt * 64;
#pragma unroll
        for (int ii = 0; ii < 2; ++ii) {
            int i = h + ii * 2;
            gload_lds16(ga + aoff[i], (char*)&sA[bsel][0] + (i * 512 + wave * 64) * 16);
        }
    };
    auto stgB = [&](int bsel, int kt, int h) {
        const __bf16* gb = Bb + kt * 64;
#pragma unroll
        for (int i = 2 * h; i < 2 * h + 2; ++i)
            gload_lds16(gb + aoff[i], (char*)&sB[bsel][0] + (i * 512 + wave * 64) * 16);
    };

    f32x4 acc[8][4] = {};
    const int nt = K >> 6;

    stgA(0, 0, 0); stgA(0, 0, 1); stgB(0, 0, 0); stgB(0, 0, 1);
    stgA(1, 1, 0); stgA(1, 1, 1); stgB(1, 1, 0); stgB(1, 1, 1);
    asm volatile("s_waitcnt vmcnt(8)" ::: "memory");   // tile0 landed
    __builtin_amdgcn_s_barrier();

    for (int t = 0; t < nt; ++t) {
        const int buf = t & 1;
        const bool pre = (t + 2 < nt);
        const __bf16* sa = &sA[buf][0];
        const __bf16* sb = &sB[buf][0];
        bf16x8 af[8], b0[4], b1[4];
        // ---- g0: ds_read A rows wm*128+0..63 (slots {0,2}) + B-nh0; MFMA Q0
#pragma unroll
        for (int m = 0; m < 4; ++m)
#pragma unroll
            for (int ks = 0; ks < 2; ++ks)
                af[m * 2 + ks] = *(const bf16x8*)&sa[(wm * 128 + m * 16 + lo) * 64 + (((ks * 4 + hi) ^ xr) << 3)];
#pragma unroll
        for (int n = 0; n < 2; ++n)
#pragma unroll
            for (int ks = 0; ks < 2; ++ks)
                b0[n * 2 + ks] = *(const bf16x8*)&sb[(wn * 64 + n * 16 + lo) * 64 + (((ks * 4 + hi) ^ xr) << 3)];
        __builtin_amdgcn_sched_barrier(0);
        __builtin_amdgcn_s_barrier();
        __builtin_amdgcn_s_setprio(1);
#pragma unroll
        for (int m = 0; m < 4; ++m)
#pragma unroll
            for (int n = 0; n < 2; ++n)
#pragma unroll
                for (int ks = 0; ks < 2; ++ks)
                    acc[m][n] = __builtin_amdgcn_mfma_f32_16x16x32_bf16(af[m * 2 + ks], b0[n * 2 + ks], acc[m][n], 0, 0, 0);
        __builtin_amdgcn_s_setprio(0);
        __builtin_amdgcn_sched_barrier(0);
        __builtin_amdgcn_s_barrier();
        // ---- g1: ds_read B-nh1; stage A-set0(t+2); MFMA Q1
#pragma unroll
        for (int n = 0; n < 2; ++n)
#pragma unroll
            for (int ks = 0; ks < 2; ++ks)
                b1[n * 2 + ks] = *(const bf16x8*)&sb[(wn * 64 + (n + 2) * 16 + lo) * 64 + (((ks * 4 + hi) ^ xr) << 3)];
        if (pre) stgA(buf, t + 2, 0);
        __builtin_amdgcn_sched_barrier(0);
        __builtin_amdgcn_s_barrier();
        __builtin_amdgcn_s_setprio(1);
#pragma unroll
        for (int m = 0; m < 4; ++m)
#pragma unroll
            for (int n = 0; n < 2; ++n)
#pragma unroll
                for (int ks = 0; ks < 2; ++ks)
                    acc[m][n + 2] = __builtin_amdgcn_mfma_f32_16x16x32_bf16(af[m * 2 + ks], b1[n * 2 + ks], acc[m][n + 2], 0, 0, 0);
        __builtin_amdgcn_s_setprio(0);
        __builtin_amdgcn_sched_barrier(0);
        __builtin_amdgcn_s_barrier();
        // ---- g2: ds_read A rows wm*128+64..127 (slots {1,3}); stage B{2,3}(t+2); MFMA Q2
#pragma unroll
        for (int m = 0; m < 4; ++m)
#pragma unroll
            for (int ks = 0; ks < 2; ++ks)
                af[m * 2 + ks] = *(const bf16x8*)&sa[(wm * 128 + (m + 4) * 16 + lo) * 64 + (((ks * 4 + hi) ^ xr) << 3)];
        if (pre) stgB(buf, t + 2, 1);
        __builtin_amdgcn_sched_barrier(0);
        __builtin_amdgcn_s_barrier();
        __builtin_amdgcn_s_setprio(1);
#pragma unroll
        for (int m = 0; m < 4; ++m)
#pragma unroll
            for (int n = 0; n < 2; ++n)
#pragma unroll
                for (int ks = 0; ks < 2; ++ks)
                    acc[m + 4][n + 2] = __builtin_amdgcn_mfma_f32_16x16x32_bf16(af[m * 2 + ks], b1[n * 2 + ks], acc[m + 4][n + 2], 0, 0, 0);
        __builtin_amdgcn_s_setprio(0);
        __builtin_amdgcn_sched_barrier(0);
        __builtin_amdgcn_s_barrier();
        // ---- g3: stage A-set1{1,3}+B{0,1}(t+2); MFMA Q3; vmcnt(8)
        if (pre) { stgA(buf, t + 2, 1); stgB(buf, t + 2, 0); }
        __builtin_amdgcn_sched_barrier(0);
        __builtin_amdgcn_s_setprio(1);
#pragma unroll
        for (int m = 0; m < 4; ++m)
#pragma unroll
            for (int n = 0; n < 2; ++n)
#pragma unroll
                for (int ks = 0; ks < 2; ++ks)
                    acc[m + 4][n] = __builtin_amdgcn_mfma_f32_16x16x32_bf16(af[m * 2 + ks], b0[n * 2 + ks], acc[m + 4][n], 0, 0, 0);
        __builtin_amdgcn_s_setprio(0);
        if (pre) asm volatile("s_waitcnt vmcnt(8)" ::: "memory");
        else     asm volatile("s_waitcnt vmcnt(0)" ::: "memory");
        __builtin_amdgcn_sched_barrier(0);
        __builtin_amdgcn_s_barrier();
    }

#pragma unroll
    for (int m = 0; m < 8; ++m) {
        int row = brow + wm * 128 + m * 16 + hi * 4;
#pragma unroll
        for (int n = 0; n < 4; ++n) {
            int col = bcol + wn * 64 + n * 16 + lo;
            if constexpr (OUTBF16) {
                __bf16* cp = (__bf16*)Cv + (size_t)row * N + col;
#pragma unroll
                for (int j = 0; j < 4; ++j)
                    cp[(size_t)j * N] = (__bf16)acc[m][n][j];
            } else {
                float* cp = (float*)Cv + (size_t)row * N + col;
#pragma unroll
                for (int j = 0; j < 4; ++j)
                    cp[(size_t)j * N] = acc[m][n][j];
            }
        }
    }
}

// --------- GEMM 256x128, BK=64, out-proj (full machine, frozen) ------------
__global__ __launch_bounds__(512, 2)
void gemm_bt8n(const __bf16* __restrict__ A, const __bf16* __restrict__ B,
               float* __restrict__ C, int M, int N, int K, int nbx) {
    __shared__ __align__(16) __bf16 sA[2][256 * 64];   // 64 KB
    __shared__ __align__(16) __bf16 sB[2][128 * 64];   // 32 KB
    const int tid = threadIdx.x;
    const int wave = tid >> 6, lane = tid & 63;
    const int lo = lane & 15, hi = lane >> 4;
    const int wm = wave >> 1, wn = wave & 1;
    const int qq = (int)gridDim.x >> 3;
    const int swz = ((int)blockIdx.x & 7) * qq + ((int)blockIdx.x >> 3);
    const int bx = swz % nbx, by = swz / nbx;
    const int brow = by * 256, bcol = bx * 128;
    const int xr = lo & 7;

    int aoff[4], boff[2];
#pragma unroll
    for (int i = 0; i < 4; ++i) {
        int n = i * 512 + tid, r = n >> 3, s = n & 7;
        aoff[i] = r * K + ((s ^ (r & 7)) << 3);
    }
#pragma unroll
    for (int i = 0; i < 2; ++i) {
        int n = i * 512 + tid, r = n >> 3, s = n & 7;
        boff[i] = r * K + ((s ^ (r & 7)) << 3);
    }
    const __bf16* Ab = A + (size_t)brow * K;
    const __bf16* Bb = B + (size_t)bcol * K;

    auto stgAall = [&](int bsel, int kt) {
        const __bf16* ga = Ab + kt * 64;
#pragma unroll
        for (int i = 0; i < 4; ++i)
            gload_lds16(ga + aoff[i], (char*)&sA[bsel][0] + (i * 512 + wave * 64) * 16);
    };
    auto stgBall = [&](int bsel, int kt) {
        const __bf16* gb = Bb + kt * 64;
#pragma unroll
        for (int i = 0; i < 2; ++i)
            gload_lds16(gb + boff[i], (char*)&sB[bsel][0] + (i * 512 + wave * 64) * 16);
    };

    f32x4 acc[4][4] = {};
    const int nt = K >> 6;

    stgAall(0, 0); stgBall(0, 0);      // 6 loads (tile0)
    stgAall(1, 1); stgBall(1, 1);      // 6 loads (tile1)
    asm volatile("s_waitcnt vmcnt(6)" ::: "memory");   // tile0 landed
    __builtin_amdgcn_s_barrier();

    for (int t = 0; t < nt; ++t) {
        const int buf = t & 1;
        const bool pre = (t + 2 < nt);
        const __bf16* sa = &sA[buf][0];
        const __bf16* sb = &sB[buf][0];
        bf16x8 af[4], b0[4], b1[4];
        // ---- g0: ds_read A m01 + B n01; MFMA Q0
#pragma unroll
        for (int m = 0; m < 2; ++m)
#pragma unroll
            for (int ks = 0; ks < 2; ++ks)
                af[m * 2 + ks] = *(const bf16x8*)&sa[(wm * 64 + m * 16 + lo) * 64 + (((ks * 4 + hi) ^ xr) << 3)];
#pragma unroll
        for (int n = 0; n < 2; ++n)
#pragma unroll
            for (int ks = 0; ks < 2; ++ks)
                b0[n * 2 + ks] = *(const bf16x8*)&sb[(wn * 64 + n * 16 + lo) * 64 + (((ks * 4 + hi) ^ xr) << 3)];
        __builtin_amdgcn_sched_barrier(0);
        __builtin_amdgcn_s_barrier();
        __builtin_amdgcn_s_setprio(1);
#pragma unroll
        for (int m = 0; m < 2; ++m)
#pragma unroll
            for (int n = 0; n < 2; ++n)
#pragma unroll
                for (int ks = 0; ks < 2; ++ks)
                    acc[m][n] = __builtin_amdgcn_mfma_f32_16x16x32_bf16(af[m * 2 + ks], b0[n * 2 + ks], acc[m][n], 0, 0, 0);
        __builtin_amdgcn_s_setprio(0);
        __builtin_amdgcn_sched_barrier(0);
        __builtin_amdgcn_s_barrier();
        // ---- g1: ds_read B n23; MFMA Q1
#pragma unroll
        for (int n = 0; n < 2; ++n)
#pragma unroll
            for (int ks = 0; ks < 2; ++ks)
                b1[n * 2 + ks] = *(const bf16x8*)&sb[(wn * 64 + (n + 2) * 16 + lo) * 64 + (((ks * 4 + hi) ^ xr) << 3)];
        __builtin_amdgcn_sched_barrier(0);
        __builtin_amdgcn_s_barrier();
        __builtin_amdgcn_s_setprio(1);
#pragma unroll
        for (int m = 0; m < 2; ++m)
#pragma unroll
            for (int n = 0; n < 2; ++n)
#pragma unroll
                for (int ks = 0; ks < 2; ++ks)
                    acc[m][n + 2] = __builtin_amdgcn_mfma_f32_16x16x32_bf16(af[m * 2 + ks], b1[n * 2 + ks], acc[m][n + 2], 0, 0, 0);
        __builtin_amdgcn_s_setprio(0);
        __builtin_amdgcn_sched_barrier(0);
        __builtin_amdgcn_s_barrier();
        // ---- g2: ds_read A m23; stage B(t+2); MFMA Q2
#pragma unroll
        for (int m = 0; m < 2; ++m)
#pragma unroll
            for (int ks = 0; ks < 2; ++ks)
                af[m * 2 + ks] = *(const bf16x8*)&sa[(wm * 64 + (m + 2) * 16 + lo) * 64 + (((ks * 4 + hi) ^ xr) << 3)];
        if (pre) stgBall(buf, t + 2);
        __builtin_amdgcn_sched_barrier(0);
        __builtin_amdgcn_s_barrier();
        __builtin_amdgcn_s_setprio(1);
#pragma unroll
        for (int m = 0; m < 2; ++m)
#pragma unroll
            for (int n = 0; n < 2; ++n)
#pragma unroll
                for (int ks = 0; ks < 2; ++ks)
                    acc[m + 2][n + 2] = __builtin_amdgcn_mfma_f32_16x16x32_bf16(af[m * 2 + ks], b1[n * 2 + ks], acc[m + 2][n + 2], 0, 0, 0);
        __builtin_amdgcn_s_setprio(0);
        __builtin_amdgcn_sched_barrier(0);
        __builtin_amdgcn_s_barrier();
        // ---- g3: stage A(t+2); MFMA Q3; vmcnt(6)
        if (pre) stgAall(buf, t + 2);
        __builtin_amdgcn_sched_barrier(0);
        __builtin_amdgcn_s_setprio(1);
#pragma unroll
        for (int m = 0; m < 2; ++m)
#pragma unroll
            for (int n = 0; n < 2; ++n)
#pragma unroll
                for (int ks = 0; ks < 2; ++ks)
                    acc[m + 2][n] = __builtin_amdgcn_mfma_f32_16x16x32_bf16(af[m * 2 + ks], b0[n * 2 + ks], acc[m + 2][n], 0, 0, 0);
        __builtin_amdgcn_s_setprio(0);
        if (pre) asm volatile("s_waitcnt vmcnt(6)" ::: "memory");
        else     asm volatile("s_waitcnt vmcnt(0)" ::: "memory");
        __builtin_amdgcn_sched_barrier(0);
        __builtin_amdgcn_s_barrier();
    }

#pragma unroll
    for (int m = 0; m < 4; ++m) {
        int row = brow + wm * 64 + m * 16 + hi * 4;
#pragma unroll
        for (int n = 0; n < 4; ++n) {
            float* cp = C + (size_t)row * N + bcol + wn * 64 + n * 16 + lo;
#pragma unroll
            for (int j = 0; j < 4; ++j)
                cp[(size_t)j * N] = acc[m][n][j];
        }
    }
}

// ---------- RMSNorm + RoPE (q,k) + V copy, from QKV bf16 (frozen) ----------
__global__ __launch_bounds__(256)
void norm_rope(const __bf16* __restrict__ QKV, const float* __restrict__ qw,
               const float* __restrict__ kw, const float* __restrict__ cosT,
               const float* __restrict__ sinT, __bf16* __restrict__ Qo,
               __bf16* __restrict__ Ko, __bf16* __restrict__ Vo) {
    const int r = blockIdx.x;            // b*S + s
    const int b = r >> 11, s = r & (SEQ - 1);
    const int wave = threadIdx.x >> 6, lane = threadIdx.x & 63;
    f32x4 cos4 = *(const f32x4*)&cosT[s * 128 + (lane & 31) * 4];
    f32x4 sin4 = *(const f32x4*)&sinT[s * 128 + (lane & 31) * 4];
#pragma unroll
    for (int ii = 0; ii < 4; ++ii) {
        int hh = wave + ii * 4;          // 0..15
        if (hh < 12) {
            bool isq = hh < 8;
            int col0 = isq ? hh * DHEAD : DMODEL + (hh - 8) * DHEAD;
            const __bf16* src = QKV + (size_t)r * 4096 + col0;
            bf16x4 xb = *(const bf16x4*)&src[lane * 4];
            float x[4];
#pragma unroll
            for (int j = 0; j < 4; ++j) x[j] = (float)xb[j];
            float ss = x[0] * x[0] + x[1] * x[1] + x[2] * x[2] + x[3] * x[3];
#pragma unroll
            for (int d2 = 1; d2 < 64; d2 <<= 1) ss += __shfl_xor(ss, d2);
            float scale = rsqrtf(ss * (1.f / DHEAD) + 1e-6f);
            const float* wp = isq ? qw : kw;
            float nx[4];
#pragma unroll
            for (int j = 0; j < 4; ++j)
                nx[j] = x[j] * scale * (1.f + wp[lane * 4 + j]);
            bf16x4 ov;
#pragma unroll
            for (int j = 0; j < 4; ++j) {
                float other = __shfl_xor(nx[j], 32);
                float rot = (lane < 32) ? -other : other;
                float v = nx[j] * cos4[j] + rot * sin4[j];
                if (isq) v *= 0.0625f;   // SCALE folded into q
                ov[j] = (__bf16)v;
            }
            __bf16* dst = isq ? (Qo + ((size_t)(b * NH + hh) * SEQ + s) * DHEAD)
                              : (Ko + ((size_t)(b * NKV + (hh - 8)) * SEQ + s) * DHEAD);
            *(bf16x4*)&dst[lane * 4] = ov;
        } else {
            int vh = hh - 12;
            const __bf16* src = QKV + (size_t)r * 4096 + 3072 + vh * DHEAD;
            bf16x4 xb = *(const bf16x4*)&src[lane * 4];
            __bf16* dst = Vo + ((size_t)(b * NKV + vh) * SEQ + s) * DHEAD;
            *(bf16x4*)&dst[lane * 4] = xb;
        }
    }
}

// ------------------ flash attention v8 (round-13 optimum) ------------------
__global__ __launch_bounds__(256)
void attn8(const __bf16* __restrict__ Q, const __bf16* __restrict__ Kb,
           const __bf16* __restrict__ Vb, __bf16* __restrict__ ctx) {
    const int bid = blockIdx.x;
    const int bk = bid & 7;            // XCD grouping: same (b,kh) -> same XCD
    const int qt = 63 - (bid >> 3);    // heavy blocks dispatch first
    const int b = bk >> 2, kh = bk & 3;
    const int q0 = qt * 32;
    const int tid = threadIdx.x;
    const int wave = tid >> 6, lane = tid & 63;
    const int lo = lane & 15, hi = lane >> 4;
    const int hsel = wave >> 1, qsub = wave & 1;
    const int h = kh * 2 + hsel;
    const int qbase = q0 + qsub * 16;
    const int q = qbase + lo;

    __shared__ __align__(16) __bf16 kbuf[2][32 * 256];   // 2 x 16 KB
    __shared__ __align__(16) __bf16 vbuf[32 * 256];      // 16 KB single

    const __bf16* Qp = Q + ((size_t)(b * NH + h) * SEQ + qbase) * DHEAD;
    const __bf16* Kp = Kb + (size_t)(b * NKV + kh) * SEQ * DHEAD;
    const __bf16* Vp = Vb + (size_t)(b * NKV + kh) * SEQ * DHEAD;

    int koff[4], voff[4];
#pragma unroll
    for (int i = 0; i < 4; ++i) {
        int n = i * 256 + tid;                 // 16B slot index
        int r = n >> 5, c = n & 31;
        koff[i] = r * 256 + ((c ^ (r & 7)) << 3);
        int st = n >> 3, w = n & 7;
        int vk = (st & 7) * 4 + (w >> 1);
        int vd = (st >> 3) * 16 + (w & 1) * 8;
        voff[i] = vk * 256 + vd;
    }

    auto stageK = [&](int bsel, int c0) {
        const __bf16* kg = Kp + (size_t)c0 * DHEAD;
        char* kd = (char*)&kbuf[bsel][0] + wave * 1024;
#pragma unroll
        for (int i = 0; i < 4; ++i) gload_lds16(kg + koff[i], kd + i * 4096);
    };
    auto stageV = [&](int c0) {
        const __bf16* vg = Vp + (size_t)c0 * DHEAD;
        char* vd = (char*)&vbuf[0] + wave * 1024;
#pragma unroll
        for (int i = 0; i < 4; ++i) gload_lds16(vg + voff[i], vd + i * 4096);
    };

    bf16x8 qf[8];
#pragma unroll
    for (int dc = 0; dc < 8; ++dc)
        qf[dc] = *(const bf16x8*)(Qp + (size_t)lo * DHEAD + dc * 32 + hi * 8);

    f32x4 o[16] = {};
    float m = -3e38f, l = 0.f;

    int kstart = q0 - SWIN; if (kstart < 0) kstart = 0;
    const int nt = (q0 + 32 - kstart) >> 5;

    stageK(0, kstart);
    asm volatile("s_waitcnt vmcnt(0)" ::: "memory");   // qf + own K(0): count exact
    int buf = 0;
    for (int t = 0; t < nt; ++t) {
        const int c0 = kstart + t * 32;
        const bool pre = (t + 1 < nt);
        stageV(c0);                          // vbuf has no readers (post end-barrier)
        if (pre) stageK(buf ^ 1, c0 + 32);
        // K(t) resident for all waves: drain to just {V(t), K(t+1)}
        if (pre) asm volatile("s_waitcnt vmcnt(8)" ::: "memory");
        else     asm volatile("s_waitcnt vmcnt(4)" ::: "memory");
        __builtin_amdgcn_sched_barrier(0);
        __builtin_amdgcn_s_barrier();
        __builtin_amdgcn_sched_barrier(0);   // pin QK^T ds_reads below barrier

        // ---- QK^T (swapped): keys c0+hi*4+j (sc0) / +16 (sc1), q = lo
        f32x4 sc0 = {}, sc1 = {};
        const __bf16* kb0 = &kbuf[buf][0];
        __builtin_amdgcn_s_setprio(1);
#pragma unroll
        for (int dc = 0; dc < 8; ++dc) {
            int u = dc * 4 + hi;
            bf16x8 kfa = *(const bf16x8*)&kb0[lo * 256 + ((u ^ (lo & 7)) << 3)];
            bf16x8 kfb = *(const bf16x8*)&kb0[(16 + lo) * 256 + ((u ^ ((16 + lo) & 7)) << 3)];
            sc0 = __builtin_amdgcn_mfma_f32_16x16x32_bf16(kfa, qf[dc], sc0, 0, 0, 0);
            sc1 = __builtin_amdgcn_mfma_f32_16x16x32_bf16(kfb, qf[dc], sc1, 0, 0, 0);
        }
        __builtin_amdgcn_s_setprio(0);

        // ---- mask + lane-parallel online softmax (state keyed q = lo)
        float s8[8];
#pragma unroll
        for (int j = 0; j < 4; ++j) {
            int ka = c0 + hi * 4 + j;
            int kb2 = ka + 16;
            s8[j]     = (ka <= q && q - ka < SWIN) ? sc0[j] : -1e30f;
            s8[4 + j] = (kb2 <= q && q - kb2 < SWIN) ? sc1[j] : -1e30f;
        }
        float pm = s8[0];
#pragma unroll
        for (int i = 1; i < 8; ++i) pm = fmaxf(pm, s8[i]);
        pm = fmaxf(pm, __shfl_xor(pm, 16));
        pm = fmaxf(pm, __shfl_xor(pm, 32));
        if (__any(pm > m + 8.f)) {             // T13 defer-max
            float mn = fmaxf(m, pm);
            float corr = __expf(m - mn);
            l *= corr;
#pragma unroll
            for (int dt = 0; dt < 16; ++dt) o[dt] *= corr;
            m = mn;
        }
        float p8[8], ps = 0.f;
#pragma unroll
        for (int i = 0; i < 8; ++i) {
            float e = __expf(s8[i] - m);
            p8[i] = (s8[i] > -9e29f) ? e : 0.f;
            ps += p8[i];
        }
        ps += __shfl_xor(ps, 16);
        ps += __shfl_xor(ps, 32);
        l += ps;

        bf16x8 paf;
#pragma unroll
        for (int i = 0; i < 8; ++i) paf[i] = (__bf16)p8[i];

        // V(t) resident for all waves: drain to just {K(t+1)}
        if (pre) asm volatile("s_waitcnt vmcnt(4)" ::: "memory");
        else     asm volatile("s_waitcnt vmcnt(0)" ::: "memory");
        __builtin_amdgcn_sched_barrier(0);
        __builtin_amdgcn_s_barrier();
        __builtin_amdgcn_sched_barrier(0);   // pin tr16 reads below barrier

        // ---- PV: flat-issue all 32 tr16 (order pinned per 8-read chunk),
        //      then counted lgkmcnt per 4-MFMA group (15 = field max).
        const __bf16* vb0 = &vbuf[0];
        bf16x4 t0[16], t1[16];
#pragma unroll
        for (int dq = 0; dq < 4; ++dq) {
#pragma unroll
            for (int u = 0; u < 4; ++u) {
                int dt = dq * 4 + u;
                t0[dt] = tr16(vb0 + (dt * 8 + hi) * 64 + lo * 4);       // k 0..3
                t1[dt] = tr16(vb0 + (dt * 8 + 4 + hi) * 64 + lo * 4);   // k 4..7
            }
            __builtin_amdgcn_sched_barrier(0);   // pin chunk issue order
        }
#pragma unroll
        for (int dq = 0; dq < 4; ++dq) {
            if (dq == 0)      asm volatile("s_waitcnt lgkmcnt(15)" ::: "memory");
            else if (dq == 1) asm volatile("s_waitcnt lgkmcnt(15)" ::: "memory");
            else if (dq == 2) asm volatile("s_waitcnt lgkmcnt(8)"  ::: "memory");
            else              asm volatile("s_waitcnt lgkmcnt(0)"  ::: "memory");
            __builtin_amdgcn_sched_barrier(0);
            __builtin_amdgcn_s_setprio(1);
#pragma unroll
            for (int u = 0; u < 4; ++u) {
                int dt = dq * 4 + u;
                bf16x8 vf;
#pragma unroll
                for (int j = 0; j < 4; ++j) { vf[j] = t0[dt][j]; vf[4 + j] = t1[dt][j]; }
                o[dt] = __builtin_amdgcn_mfma_f32_16x16x32_bf16(vf, paf, o[dt], 0, 0, 0);
            }
            __builtin_amdgcn_s_setprio(0);
        }
        __builtin_amdgcn_sched_barrier(0);
        __builtin_amdgcn_s_barrier();        // raw WAR barrier: PV reads retired
        __builtin_amdgcn_sched_barrier(0);
        buf ^= 1;
    }

    const float invl = 1.0f / l;
    __bf16* cp = ctx + ((size_t)(b * SEQ + q)) * (NH * DHEAD) + h * DHEAD;
#pragma unroll
    for (int dt = 0; dt < 16; ++dt) {
        bf16x4 w;
#pragma unroll
        for (int j = 0; j < 4; ++j) w[j] = (__bf16)(o[dt][j] * invl);
        *(bf16x4*)&cp[dt * 16 + hi * 4] = w;
    }
}

// ---------------------------------------------------------------------------
extern "C" void kernel_launch(void* const* d_in, const int* in_sizes, int n_in,
                              void* d_out, int out_size, void* d_ws, size_t ws_size,
                              hipStream_t stream) {
    const float* hs = (const float*)d_in[0];
    const float* Wq = (const float*)d_in[1];
    const float* Wk = (const float*)d_in[2];
    const float* Wv = (const float*)d_in[3];
    const float* Wo = (const float*)d_in[4];
    const float* qw = (const float*)d_in[5];
    const float* kw = (const float*)d_in[6];
    float* out = (float*)d_out;

    char* ws = (char*)d_ws;
    size_t off = 0;
    auto alloc = [&](size_t bytes) {
        char* p = ws + off;
        off += (bytes + 255) & ~(size_t)255;
        return p;
    };
    const int M = NB * SEQ;                       // 4096
    __bf16* hsB   = (__bf16*)alloc((size_t)M * DMODEL * 2);
    __bf16* WqkvB = (__bf16*)alloc((size_t)4096 * DMODEL * 2);
    __bf16* WoB   = (__bf16*)alloc((size_t)DMODEL * DMODEL * 2);
    __bf16* QKVb  = (__bf16*)alloc((size_t)M * 4096 * 2);
    __bf16* Qb    = (__bf16*)alloc((size_t)M * 2048 * 2);
    __bf16* Kbf   = (__bf16*)alloc((size_t)M * 1024 * 2);
    __bf16* Vbf   = (__bf16*)alloc((size_t)M * 1024 * 2);
    float*  cosT  = (float*) alloc((size_t)SEQ * 128 * 4);
    float*  sinT  = (float*) alloc((size_t)SEQ * 128 * 4);
    __bf16* ctxB  = QKVb;                         // reuse: QKV dead after norm_rope

    cvt_rope<<<21504, 256, 0, stream>>>(hs, Wq, Wk, Wv, Wo,
                                        hsB, WqkvB, WqkvB + (size_t)2048 * 2048,
                                        WqkvB + (size_t)3072 * 2048, WoB, cosT, sinT);

    // fused QKV projection: 256 blocks (16x16 tiles of 256), bf16 output
    gemm_bt8<1><<<256, 512, 0, stream>>>(hsB, WqkvB, QKVb, M, 4096, DMODEL, 16);

    norm_rope<<<M, 256, 0, stream>>>(QKVb, qw, kw, cosT, sinT, Qb, Kbf, Vbf);

    attn8<<<512, 256, 0, stream>>>(Qb, Kbf, Vbf, ctxB);

    // output projection: 256 blocks (16x16 tiles of 256x128)
    gemm_bt8n<<<256, 512, 0, stream>>>(ctxB, WoB, out, M, DMODEL, DMODEL, 16);
}

// Round 17
// 198.218 us; speedup vs baseline: 2.0718x; 1.0330x over previous
//
#include <hip/hip_runtime.h>
#include <hip/hip_bf16.h>

// ---------------------------------------------------------------------------
// Gemma sliding-window attention layer, MI355X round 17.
// norm_rope fused into the QKV GEMM epilogue (each 256-col tile = exactly one
// head): stage acc->LDS as bf16 (bit-identical to the old HBM round trip),
// then per-row RMSNorm+RoPE / V-copy and direct Q/K/V writes. QKVb buffer and
// the norm_rope kernel deleted. K-loop, attn8, gemm_bt8n, cvt frozen (r13).
// ---------------------------------------------------------------------------

typedef __bf16 bf16x8 __attribute__((ext_vector_type(8)));
typedef __bf16 bf16x4 __attribute__((ext_vector_type(4)));
typedef float f32x4 __attribute__((ext_vector_type(4)));

#define NB 2
#define SEQ 2048
#define DMODEL 2048
#define NH 8
#define NKV 4
#define DHEAD 256
#define SWIN 1024

#define AS1 __attribute__((address_space(1)))
#define AS3 __attribute__((address_space(3)))

static __device__ __forceinline__ void gload_lds16(const void* g, void* l) {
    __builtin_amdgcn_global_load_lds((const AS1 void*)g, (AS3 void*)l, 16, 0, 0);
}

static __device__ __forceinline__ bf16x4 tr16(const __bf16* p) {
    bf16x4 r;
    asm volatile("ds_read_b64_tr_b16 %0, %1" : "=v"(r) : "v"((const AS3 __bf16*)p));
    return r;
}

// ------------------- merged f32->bf16 convert + RoPE table ------------------
__global__ void cvt_rope(const float* __restrict__ s0, const float* __restrict__ s1,
                         const float* __restrict__ s2, const float* __restrict__ s3,
                         const float* __restrict__ s4, __bf16* __restrict__ d0,
                         __bf16* __restrict__ d1, __bf16* __restrict__ d2,
                         __bf16* __restrict__ d3, __bf16* __restrict__ d4,
                         float* __restrict__ cosT, float* __restrict__ sinT) {
    if (blockIdx.x >= 20480) {
        int idx = (blockIdx.x - 20480) * 256 + threadIdx.x;   // < 262144
        int s = idx >> 7, i = idx & 127;
        float fr = (float)s * __expf(-(float)i * 0.0719557843f);  // ln(1e4)/128
        cosT[idx] = cosf(fr);
        sinT[idx] = sinf(fr);
        return;
    }
    int i = blockIdx.x * 256 + threadIdx.x;      // covers exactly 5242880
    const float* src; __bf16* dst;
    if (i < 2097152) { src = s0; dst = d0; }
    else if (i < 3145728) { i -= 2097152; src = s1; dst = d1; }
    else if (i < 3670016) { i -= 3145728; src = s2; dst = d2; }
    else if (i < 4194304) { i -= 3670016; src = s3; dst = d3; }
    else                  { i -= 4194304; src = s4; dst = d4; }
    f32x4 v = ((const f32x4*)src)[i];
    bf16x4 o;
#pragma unroll
    for (int j = 0; j < 4; ++j) o[j] = (__bf16)v[j];
    ((bf16x4*)dst)[i] = o;
}

// --------- QKV GEMM 256x256, BK=64, 8-phase pipelined + fused norm/rope ----
// C = A[M,K] * B[N,K]^T computed in acc; epilogue stages acc->LDS bf16
// ([256][264] padded, overlaid on the staging smem), then per-row
// RMSNorm+RoPE (Q: bx<8, K: bx 8-11) or plain copy (V: bx 12-15), writing
// Qo/Ko/Vo directly. Math is bit-identical to the old QKV->norm_rope path.
__global__ __launch_bounds__(512, 2)
void gemm_qkv(const __bf16* __restrict__ A, const __bf16* __restrict__ B,
              const float* __restrict__ qw, const float* __restrict__ kw,
              const float* __restrict__ cosT, const float* __restrict__ sinT,
              __bf16* __restrict__ Qo, __bf16* __restrict__ Ko,
              __bf16* __restrict__ Vo, int M, int N, int K, int nbx) {
    __shared__ __align__(16) __bf16 smem[67584];       // 132 KB
    // gemm phase layout: sA[b] = smem + b*16384, sB[b] = smem + 32768 + b*16384
    const int tid = threadIdx.x;
    const int wave = tid >> 6, lane = tid & 63;
    const int lo = lane & 15, hi = lane >> 4;
    const int wm = wave >> 2, wn = wave & 3;
    const int qq = (int)gridDim.x >> 3;
    const int swz = ((int)blockIdx.x & 7) * qq + ((int)blockIdx.x >> 3);
    const int bx = swz % nbx, by = swz / nbx;
    const int brow = by * 256;
    const int xr = lo & 7;

    int aoff[4];
#pragma unroll
    for (int i = 0; i < 4; ++i) {
        int n = i * 512 + tid, r = n >> 3, s = n & 7;
        aoff[i] = r * K + ((s ^ (r & 7)) << 3);   // pre-swizzled global source
    }
    const __bf16* Ab = A + (size_t)brow * K;
    const __bf16* Bb = B + (size_t)(bx * 256) * K;

    auto stgA = [&](int bsel, int kt, int h) {
        const __bf16* ga = Ab + kt * 64;
#pragma unroll
        for (int ii = 0; ii < 2; ++ii) {
            int i = h + ii * 2;
            gload_lds16(ga + aoff[i], (char*)(smem + bsel * 16384) + (i * 512 + wave * 64) * 16);
        }
    };
    auto stgB = [&](int bsel, int kt, int h) {
        const __bf16* gb = Bb + kt * 64;
#pragma unroll
        for (int i = 2 * h; i < 2 * h + 2; ++i)
            gload_lds16(gb + aoff[i], (char*)(smem + 32768 + bsel * 16384) + (i * 512 + wave * 64) * 16);
    };

    f32x4 acc[8][4] = {};
    const int nt = K >> 6;

    stgA(0, 0, 0); stgA(0, 0, 1); stgB(0, 0, 0); stgB(0, 0, 1);
    stgA(1, 1, 0); stgA(1, 1, 1); stgB(1, 1, 0); stgB(1, 1, 1);
    asm volatile("s_waitcnt vmcnt(8)" ::: "memory");   // tile0 landed
    __builtin_amdgcn_s_barrier();

    for (int t = 0; t < nt; ++t) {
        const int buf = t & 1;
        const bool pre = (t + 2 < nt);
        const __bf16* sa = smem + buf * 16384;
        const __bf16* sb = smem + 32768 + buf * 16384;
        bf16x8 af[8], b0[4], b1[4];
        // ---- g0: ds_read A rows wm*128+0..63 (slots {0,2}) + B-nh0; MFMA Q0
#pragma unroll
        for (int m = 0; m < 4; ++m)
#pragma unroll
            for (int ks = 0; ks < 2; ++ks)
                af[m * 2 + ks] = *(const bf16x8*)&sa[(wm * 128 + m * 16 + lo) * 64 + (((ks * 4 + hi) ^ xr) << 3)];
#pragma unroll
        for (int n = 0; n < 2; ++n)
#pragma unroll
            for (int ks = 0; ks < 2; ++ks)
                b0[n * 2 + ks] = *(const bf16x8*)&sb[(wn * 64 + n * 16 + lo) * 64 + (((ks * 4 + hi) ^ xr) << 3)];
        __builtin_amdgcn_sched_barrier(0);
        __builtin_amdgcn_s_barrier();
        __builtin_amdgcn_s_setprio(1);
#pragma unroll
        for (int m = 0; m < 4; ++m)
#pragma unroll
            for (int n = 0; n < 2; ++n)
#pragma unroll
                for (int ks = 0; ks < 2; ++ks)
                    acc[m][n] = __builtin_amdgcn_mfma_f32_16x16x32_bf16(af[m * 2 + ks], b0[n * 2 + ks], acc[m][n], 0, 0, 0);
        __builtin_amdgcn_s_setprio(0);
        __builtin_amdgcn_sched_barrier(0);
        __builtin_amdgcn_s_barrier();
        // ---- g1: ds_read B-nh1; stage A-set0(t+2); MFMA Q1
#pragma unroll
        for (int n = 0; n < 2; ++n)
#pragma unroll
            for (int ks = 0; ks < 2; ++ks)
                b1[n * 2 + ks] = *(const bf16x8*)&sb[(wn * 64 + (n + 2) * 16 + lo) * 64 + (((ks * 4 + hi) ^ xr) << 3)];
        if (pre) stgA(buf, t + 2, 0);
        __builtin_amdgcn_sched_barrier(0);
        __builtin_amdgcn_s_barrier();
        __builtin_amdgcn_s_setprio(1);
#pragma unroll
        for (int m = 0; m < 4; ++m)
#pragma unroll
            for (int n = 0; n < 2; ++n)
#pragma unroll
                for (int ks = 0; ks < 2; ++ks)
                    acc[m][n + 2] = __builtin_amdgcn_mfma_f32_16x16x32_bf16(af[m * 2 + ks], b1[n * 2 + ks], acc[m][n + 2], 0, 0, 0);
        __builtin_amdgcn_s_setprio(0);
        __builtin_amdgcn_sched_barrier(0);
        __builtin_amdgcn_s_barrier();
        // ---- g2: ds_read A rows wm*128+64..127 (slots {1,3}); stage B{2,3}(t+2); MFMA Q2
#pragma unroll
        for (int m = 0; m < 4; ++m)
#pragma unroll
            for (int ks = 0; ks < 2; ++ks)
                af[m * 2 + ks] = *(const bf16x8*)&sa[(wm * 128 + (m + 4) * 16 + lo) * 64 + (((ks * 4 + hi) ^ xr) << 3)];
        if (pre) stgB(buf, t + 2, 1);
        __builtin_amdgcn_sched_barrier(0);
        __builtin_amdgcn_s_barrier();
        __builtin_amdgcn_s_setprio(1);
#pragma unroll
        for (int m = 0; m < 4; ++m)
#pragma unroll
            for (int n = 0; n < 2; ++n)
#pragma unroll
                for (int ks = 0; ks < 2; ++ks)
                    acc[m + 4][n + 2] = __builtin_amdgcn_mfma_f32_16x16x32_bf16(af[m * 2 + ks], b1[n * 2 + ks], acc[m + 4][n + 2], 0, 0, 0);
        __builtin_amdgcn_s_setprio(0);
        __builtin_amdgcn_sched_barrier(0);
        __builtin_amdgcn_s_barrier();
        // ---- g3: stage A-set1{1,3}+B{0,1}(t+2); MFMA Q3; vmcnt(8)
        if (pre) { stgA(buf, t + 2, 1); stgB(buf, t + 2, 0); }
        __builtin_amdgcn_sched_barrier(0);
        __builtin_amdgcn_s_setprio(1);
#pragma unroll
        for (int m = 0; m < 4; ++m)
#pragma unroll
            for (int n = 0; n < 2; ++n)
#pragma unroll
                for (int ks = 0; ks < 2; ++ks)
                    acc[m + 4][n] = __builtin_amdgcn_mfma_f32_16x16x32_bf16(af[m * 2 + ks], b0[n * 2 + ks], acc[m + 4][n], 0, 0, 0);
        __builtin_amdgcn_s_setprio(0);
        if (pre) asm volatile("s_waitcnt vmcnt(8)" ::: "memory");
        else     asm volatile("s_waitcnt vmcnt(0)" ::: "memory");
        __builtin_amdgcn_sched_barrier(0);
        __builtin_amdgcn_s_barrier();
    }

    // ---- fused epilogue -----------------------------------------------------
    __syncthreads();                      // K-loop fully retired; smem reusable
    {
        // stage acc as bf16 into [256][264] (identical rounding to the old
        // QKV HBM round-trip)
#pragma unroll
        for (int m = 0; m < 8; ++m)
#pragma unroll
            for (int n = 0; n < 4; ++n) {
                int lr = wm * 128 + m * 16 + hi * 4;
                int lc = wn * 64 + n * 16 + lo;
#pragma unroll
                for (int j = 0; j < 4; ++j)
                    smem[(lr + j) * 264 + lc] = (__bf16)acc[m][n][j];
            }
        __syncthreads();

        const bool isq = bx < 8;
        const bool isv = bx >= 12;
        float w4[4];
        if (!isv) {
            const float* wp = isq ? qw : kw;
#pragma unroll
            for (int j = 0; j < 4; ++j) w4[j] = 1.f + wp[lane * 4 + j];
        }
        __bf16* hbase = isq ? Qo : (isv ? Vo : Ko);
        const int hidx = isq ? bx : (isv ? bx - 12 : bx - 8);
        const int nheads = isq ? NH : NKV;

        for (int rr = 0; rr < 32; ++rr) {
            int lr = wave * 32 + rr;
            int gs = brow + lr;
            int bb = gs >> 11, s = gs & (SEQ - 1);
            bf16x4 xb = *(const bf16x4*)&smem[lr * 264 + lane * 4];
            bf16x4 ov;
            if (isv) {
                ov = xb;
            } else {
                float x[4];
#pragma unroll
                for (int j = 0; j < 4; ++j) x[j] = (float)xb[j];
                float ss = x[0] * x[0] + x[1] * x[1] + x[2] * x[2] + x[3] * x[3];
#pragma unroll
                for (int d2 = 1; d2 < 64; d2 <<= 1) ss += __shfl_xor(ss, d2);
                float scale = rsqrtf(ss * (1.f / DHEAD) + 1e-6f);
                float nx[4];
#pragma unroll
                for (int j = 0; j < 4; ++j) nx[j] = x[j] * scale * w4[j];
                f32x4 cos4 = *(const f32x4*)&cosT[s * 128 + (lane & 31) * 4];
                f32x4 sin4 = *(const f32x4*)&sinT[s * 128 + (lane & 31) * 4];
#pragma unroll
                for (int j = 0; j < 4; ++j) {
                    float other = __shfl_xor(nx[j], 32);
                    float rot = (lane < 32) ? -other : other;
                    float v = nx[j] * cos4[j] + rot * sin4[j];
                    if (isq) v *= 0.0625f;   // SCALE folded into q
                    ov[j] = (__bf16)v;
                }
            }
            __bf16* dst = hbase + ((size_t)(bb * nheads + hidx) * SEQ + s) * DHEAD;
            *(bf16x4*)&dst[lane * 4] = ov;
        }
    }
}

// --------- GEMM 256x128, BK=64, out-proj (full machine, frozen) ------------
__global__ __launch_bounds__(512, 2)
void gemm_bt8n(const __bf16* __restrict__ A, const __bf16* __restrict__ B,
               float* __restrict__ C, int M, int N, int K, int nbx) {
    __shared__ __align__(16) __bf16 sA[2][256 * 64];   // 64 KB
    __shared__ __align__(16) __bf16 sB[2][128 * 64];   // 32 KB
    const int tid = threadIdx.x;
    const int wave = tid >> 6, lane = tid & 63;
    const int lo = lane & 15, hi = lane >> 4;
    const int wm = wave >> 1, wn = wave & 1;
    const int qq = (int)gridDim.x >> 3;
    const int swz = ((int)blockIdx.x & 7) * qq + ((int)blockIdx.x >> 3);
    const int bx = swz % nbx, by = swz / nbx;
    const int brow = by * 256, bcol = bx * 128;
    const int xr = lo & 7;

    int aoff[4], boff[2];
#pragma unroll
    for (int i = 0; i < 4; ++i) {
        int n = i * 512 + tid, r = n >> 3, s = n & 7;
        aoff[i] = r * K + ((s ^ (r & 7)) << 3);
    }
#pragma unroll
    for (int i = 0; i < 2; ++i) {
        int n = i * 512 + tid, r = n >> 3, s = n & 7;
        boff[i] = r * K + ((s ^ (r & 7)) << 3);
    }
    const __bf16* Ab = A + (size_t)brow * K;
    const __bf16* Bb = B + (size_t)bcol * K;

    auto stgAall = [&](int bsel, int kt) {
        const __bf16* ga = Ab + kt * 64;
#pragma unroll
        for (int i = 0; i < 4; ++i)
            gload_lds16(ga + aoff[i], (char*)&sA[bsel][0] + (i * 512 + wave * 64) * 16);
    };
    auto stgBall = [&](int bsel, int kt) {
        const __bf16* gb = Bb + kt * 64;
#pragma unroll
        for (int i = 0; i < 2; ++i)
            gload_lds16(gb + boff[i], (char*)&sB[bsel][0] + (i * 512 + wave * 64) * 16);
    };

    f32x4 acc[4][4] = {};
    const int nt = K >> 6;

    stgAall(0, 0); stgBall(0, 0);      // 6 loads (tile0)
    stgAall(1, 1); stgBall(1, 1);      // 6 loads (tile1)
    asm volatile("s_waitcnt vmcnt(6)" ::: "memory");   // tile0 landed
    __builtin_amdgcn_s_barrier();

    for (int t = 0; t < nt; ++t) {
        const int buf = t & 1;
        const bool pre = (t + 2 < nt);
        const __bf16* sa = &sA[buf][0];
        const __bf16* sb = &sB[buf][0];
        bf16x8 af[4], b0[4], b1[4];
        // ---- g0: ds_read A m01 + B n01; MFMA Q0
#pragma unroll
        for (int m = 0; m < 2; ++m)
#pragma unroll
            for (int ks = 0; ks < 2; ++ks)
                af[m * 2 + ks] = *(const bf16x8*)&sa[(wm * 64 + m * 16 + lo) * 64 + (((ks * 4 + hi) ^ xr) << 3)];
#pragma unroll
        for (int n = 0; n < 2; ++n)
#pragma unroll
            for (int ks = 0; ks < 2; ++ks)
                b0[n * 2 + ks] = *(const bf16x8*)&sb[(wn * 64 + n * 16 + lo) * 64 + (((ks * 4 + hi) ^ xr) << 3)];
        __builtin_amdgcn_sched_barrier(0);
        __builtin_amdgcn_s_barrier();
        __builtin_amdgcn_s_setprio(1);
#pragma unroll
        for (int m = 0; m < 2; ++m)
#pragma unroll
            for (int n = 0; n < 2; ++n)
#pragma unroll
                for (int ks = 0; ks < 2; ++ks)
                    acc[m][n] = __builtin_amdgcn_mfma_f32_16x16x32_bf16(af[m * 2 + ks], b0[n * 2 + ks], acc[m][n], 0, 0, 0);
        __builtin_amdgcn_s_setprio(0);
        __builtin_amdgcn_sched_barrier(0);
        __builtin_amdgcn_s_barrier();
        // ---- g1: ds_read B n23; MFMA Q1
#pragma unroll
        for (int n = 0; n < 2; ++n)
#pragma unroll
            for (int ks = 0; ks < 2; ++ks)
                b1[n * 2 + ks] = *(const bf16x8*)&sb[(wn * 64 + (n + 2) * 16 + lo) * 64 + (((ks * 4 + hi) ^ xr) << 3)];
        __builtin_amdgcn_sched_barrier(0);
        __builtin_amdgcn_s_barrier();
        __builtin_amdgcn_s_setprio(1);
#pragma unroll
        for (int m = 0; m < 2; ++m)
#pragma unroll
            for (int n = 0; n < 2; ++n)
#pragma unroll
                for (int ks = 0; ks < 2; ++ks)
                    acc[m][n + 2] = __builtin_amdgcn_mfma_f32_16x16x32_bf16(af[m * 2 + ks], b1[n * 2 + ks], acc[m][n + 2], 0, 0, 0);
        __builtin_amdgcn_s_setprio(0);
        __builtin_amdgcn_sched_barrier(0);
        __builtin_amdgcn_s_barrier();
        // ---- g2: ds_read A m23; stage B(t+2); MFMA Q2
#pragma unroll
        for (int m = 0; m < 2; ++m)
#pragma unroll
            for (int ks = 0; ks < 2; ++ks)
                af[m * 2 + ks] = *(const bf16x8*)&sa[(wm * 64 + (m + 2) * 16 + lo) * 64 + (((ks * 4 + hi) ^ xr) << 3)];
        if (pre) stgBall(buf, t + 2);
        __builtin_amdgcn_sched_barrier(0);
        __builtin_amdgcn_s_barrier();
        __builtin_amdgcn_s_setprio(1);
#pragma unroll
        for (int m = 0; m < 2; ++m)
#pragma unroll
            for (int n = 0; n < 2; ++n)
#pragma unroll
                for (int ks = 0; ks < 2; ++ks)
                    acc[m + 2][n + 2] = __builtin_amdgcn_mfma_f32_16x16x32_bf16(af[m * 2 + ks], b1[n * 2 + ks], acc[m + 2][n + 2], 0, 0, 0);
        __builtin_amdgcn_s_setprio(0);
        __builtin_amdgcn_sched_barrier(0);
        __builtin_amdgcn_s_barrier();
        // ---- g3: stage A(t+2); MFMA Q3; vmcnt(6)
        if (pre) stgAall(buf, t + 2);
        __builtin_amdgcn_sched_barrier(0);
        __builtin_amdgcn_s_setprio(1);
#pragma unroll
        for (int m = 0; m < 2; ++m)
#pragma unroll
            for (int n = 0; n < 2; ++n)
#pragma unroll
                for (int ks = 0; ks < 2; ++ks)
                    acc[m + 2][n] = __builtin_amdgcn_mfma_f32_16x16x32_bf16(af[m * 2 + ks], b0[n * 2 + ks], acc[m + 2][n], 0, 0, 0);
        __builtin_amdgcn_s_setprio(0);
        if (pre) asm volatile("s_waitcnt vmcnt(6)" ::: "memory");
        else     asm volatile("s_waitcnt vmcnt(0)" ::: "memory");
        __builtin_amdgcn_sched_barrier(0);
        __builtin_amdgcn_s_barrier();
    }

#pragma unroll
    for (int m = 0; m < 4; ++m) {
        int row = brow + wm * 64 + m * 16 + hi * 4;
#pragma unroll
        for (int n = 0; n < 4; ++n) {
            float* cp = C + (size_t)row * N + bcol + wn * 64 + n * 16 + lo;
#pragma unroll
            for (int j = 0; j < 4; ++j)
                cp[(size_t)j * N] = acc[m][n][j];
        }
    }
}

// ------------------ flash attention v8 (round-13 optimum, frozen) ----------
__global__ __launch_bounds__(256)
void attn8(const __bf16* __restrict__ Q, const __bf16* __restrict__ Kb,
           const __bf16* __restrict__ Vb, __bf16* __restrict__ ctx) {
    const int bid = blockIdx.x;
    const int bk = bid & 7;            // XCD grouping: same (b,kh) -> same XCD
    const int qt = 63 - (bid >> 3);    // heavy blocks dispatch first
    const int b = bk >> 2, kh = bk & 3;
    const int q0 = qt * 32;
    const int tid = threadIdx.x;
    const int wave = tid >> 6, lane = tid & 63;
    const int lo = lane & 15, hi = lane >> 4;
    const int hsel = wave >> 1, qsub = wave & 1;
    const int h = kh * 2 + hsel;
    const int qbase = q0 + qsub * 16;
    const int q = qbase + lo;

    __shared__ __align__(16) __bf16 kbuf[2][32 * 256];   // 2 x 16 KB
    __shared__ __align__(16) __bf16 vbuf[32 * 256];      // 16 KB single

    const __bf16* Qp = Q + ((size_t)(b * NH + h) * SEQ + qbase) * DHEAD;
    const __bf16* Kp = Kb + (size_t)(b * NKV + kh) * SEQ * DHEAD;
    const __bf16* Vp = Vb + (size_t)(b * NKV + kh) * SEQ * DHEAD;

    int koff[4], voff[4];
#pragma unroll
    for (int i = 0; i < 4; ++i) {
        int n = i * 256 + tid;                 // 16B slot index
        int r = n >> 5, c = n & 31;
        koff[i] = r * 256 + ((c ^ (r & 7)) << 3);
        int st = n >> 3, w = n & 7;
        int vk = (st & 7) * 4 + (w >> 1);
        int vd = (st >> 3) * 16 + (w & 1) * 8;
        voff[i] = vk * 256 + vd;
    }

    auto stageK = [&](int bsel, int c0) {
        const __bf16* kg = Kp + (size_t)c0 * DHEAD;
        char* kd = (char*)&kbuf[bsel][0] + wave * 1024;
#pragma unroll
        for (int i = 0; i < 4; ++i) gload_lds16(kg + koff[i], kd + i * 4096);
    };
    auto stageV = [&](int c0) {
        const __bf16* vg = Vp + (size_t)c0 * DHEAD;
        char* vd = (char*)&vbuf[0] + wave * 1024;
#pragma unroll
        for (int i = 0; i < 4; ++i) gload_lds16(vg + voff[i], vd + i * 4096);
    };

    bf16x8 qf[8];
#pragma unroll
    for (int dc = 0; dc < 8; ++dc)
        qf[dc] = *(const bf16x8*)(Qp + (size_t)lo * DHEAD + dc * 32 + hi * 8);

    f32x4 o[16] = {};
    float m = -3e38f, l = 0.f;

    int kstart = q0 - SWIN; if (kstart < 0) kstart = 0;
    const int nt = (q0 + 32 - kstart) >> 5;

    stageK(0, kstart);
    asm volatile("s_waitcnt vmcnt(0)" ::: "memory");   // qf + own K(0): count exact
    int buf = 0;
    for (int t = 0; t < nt; ++t) {
        const int c0 = kstart + t * 32;
        const bool pre = (t + 1 < nt);
        stageV(c0);                          // vbuf has no readers (post end-barrier)
        if (pre) stageK(buf ^ 1, c0 + 32);
        // K(t) resident for all waves: drain to just {V(t), K(t+1)}
        if (pre) asm volatile("s_waitcnt vmcnt(8)" ::: "memory");
        else     asm volatile("s_waitcnt vmcnt(4)" ::: "memory");
        __builtin_amdgcn_sched_barrier(0);
        __builtin_amdgcn_s_barrier();
        __builtin_amdgcn_sched_barrier(0);   // pin QK^T ds_reads below barrier

        // ---- QK^T (swapped): keys c0+hi*4+j (sc0) / +16 (sc1), q = lo
        f32x4 sc0 = {}, sc1 = {};
        const __bf16* kb0 = &kbuf[buf][0];
        __builtin_amdgcn_s_setprio(1);
#pragma unroll
        for (int dc = 0; dc < 8; ++dc) {
            int u = dc * 4 + hi;
            bf16x8 kfa = *(const bf16x8*)&kb0[lo * 256 + ((u ^ (lo & 7)) << 3)];
            bf16x8 kfb = *(const bf16x8*)&kb0[(16 + lo) * 256 + ((u ^ ((16 + lo) & 7)) << 3)];
            sc0 = __builtin_amdgcn_mfma_f32_16x16x32_bf16(kfa, qf[dc], sc0, 0, 0, 0);
            sc1 = __builtin_amdgcn_mfma_f32_16x16x32_bf16(kfb, qf[dc], sc1, 0, 0, 0);
        }
        __builtin_amdgcn_s_setprio(0);

        // ---- mask + lane-parallel online softmax (state keyed q = lo)
        float s8[8];
#pragma unroll
        for (int j = 0; j < 4; ++j) {
            int ka = c0 + hi * 4 + j;
            int kb2 = ka + 16;
            s8[j]     = (ka <= q && q - ka < SWIN) ? sc0[j] : -1e30f;
            s8[4 + j] = (kb2 <= q && q - kb2 < SWIN) ? sc1[j] : -1e30f;
        }
        float pm = s8[0];
#pragma unroll
        for (int i = 1; i < 8; ++i) pm = fmaxf(pm, s8[i]);
        pm = fmaxf(pm, __shfl_xor(pm, 16));
        pm = fmaxf(pm, __shfl_xor(pm, 32));
        if (__any(pm > m + 8.f)) {             // T13 defer-max
            float mn = fmaxf(m, pm);
            float corr = __expf(m - mn);
            l *= corr;
#pragma unroll
            for (int dt = 0; dt < 16; ++dt) o[dt] *= corr;
            m = mn;
        }
        float p8[8], ps = 0.f;
#pragma unroll
        for (int i = 0; i < 8; ++i) {
            float e = __expf(s8[i] - m);
            p8[i] = (s8[i] > -9e29f) ? e : 0.f;
            ps += p8[i];
        }
        ps += __shfl_xor(ps, 16);
        ps += __shfl_xor(ps, 32);
        l += ps;

        bf16x8 paf;
#pragma unroll
        for (int i = 0; i < 8; ++i) paf[i] = (__bf16)p8[i];

        // V(t) resident for all waves: drain to just {K(t+1)}
        if (pre) asm volatile("s_waitcnt vmcnt(4)" ::: "memory");
        else     asm volatile("s_waitcnt vmcnt(0)" ::: "memory");
        __builtin_amdgcn_sched_barrier(0);
        __builtin_amdgcn_s_barrier();
        __builtin_amdgcn_sched_barrier(0);   // pin tr16 reads below barrier

        // ---- PV: flat-issue all 32 tr16 (order pinned per 8-read chunk),
        //      then counted lgkmcnt per 4-MFMA group (15 = field max).
        const __bf16* vb0 = &vbuf[0];
        bf16x4 t0[16], t1[16];
#pragma unroll
        for (int dq = 0; dq < 4; ++dq) {
#pragma unroll
            for (int u = 0; u < 4; ++u) {
                int dt = dq * 4 + u;
                t0[dt] = tr16(vb0 + (dt * 8 + hi) * 64 + lo * 4);       // k 0..3
                t1[dt] = tr16(vb0 + (dt * 8 + 4 + hi) * 64 + lo * 4);   // k 4..7
            }
            __builtin_amdgcn_sched_barrier(0);   // pin chunk issue order
        }
#pragma unroll
        for (int dq = 0; dq < 4; ++dq) {
            if (dq == 0)      asm volatile("s_waitcnt lgkmcnt(15)" ::: "memory");
            else if (dq == 1) asm volatile("s_waitcnt lgkmcnt(15)" ::: "memory");
            else if (dq == 2) asm volatile("s_waitcnt lgkmcnt(8)"  ::: "memory");
            else              asm volatile("s_waitcnt lgkmcnt(0)"  ::: "memory");
            __builtin_amdgcn_sched_barrier(0);
            __builtin_amdgcn_s_setprio(1);
#pragma unroll
            for (int u = 0; u < 4; ++u) {
                int dt = dq * 4 + u;
                bf16x8 vf;
#pragma unroll
                for (int j = 0; j < 4; ++j) { vf[j] = t0[dt][j]; vf[4 + j] = t1[dt][j]; }
                o[dt] = __builtin_amdgcn_mfma_f32_16x16x32_bf16(vf, paf, o[dt], 0, 0, 0);
            }
            __builtin_amdgcn_s_setprio(0);
        }
        __builtin_amdgcn_sched_barrier(0);
        __builtin_amdgcn_s_barrier();        // raw WAR barrier: PV reads retired
        __builtin_amdgcn_sched_barrier(0);
        buf ^= 1;
    }

    const float invl = 1.0f / l;
    __bf16* cp = ctx + ((size_t)(b * SEQ + q)) * (NH * DHEAD) + h * DHEAD;
#pragma unroll
    for (int dt = 0; dt < 16; ++dt) {
        bf16x4 w;
#pragma unroll
        for (int j = 0; j < 4; ++j) w[j] = (__bf16)(o[dt][j] * invl);
        *(bf16x4*)&cp[dt * 16 + hi * 4] = w;
    }
}

// ---------------------------------------------------------------------------
extern "C" void kernel_launch(void* const* d_in, const int* in_sizes, int n_in,
                              void* d_out, int out_size, void* d_ws, size_t ws_size,
                              hipStream_t stream) {
    const float* hs = (const float*)d_in[0];
    const float* Wq = (const float*)d_in[1];
    const float* Wk = (const float*)d_in[2];
    const float* Wv = (const float*)d_in[3];
    const float* Wo = (const float*)d_in[4];
    const float* qw = (const float*)d_in[5];
    const float* kw = (const float*)d_in[6];
    float* out = (float*)d_out;

    char* ws = (char*)d_ws;
    size_t off = 0;
    auto alloc = [&](size_t bytes) {
        char* p = ws + off;
        off += (bytes + 255) & ~(size_t)255;
        return p;
    };
    const int M = NB * SEQ;                       // 4096
    __bf16* hsB   = (__bf16*)alloc((size_t)M * DMODEL * 2);
    __bf16* WqkvB = (__bf16*)alloc((size_t)4096 * DMODEL * 2);
    __bf16* WoB   = (__bf16*)alloc((size_t)DMODEL * DMODEL * 2);
    __bf16* Qb    = (__bf16*)alloc((size_t)M * 2048 * 2);
    __bf16* Kbf   = (__bf16*)alloc((size_t)M * 1024 * 2);
    __bf16* Vbf   = (__bf16*)alloc((size_t)M * 1024 * 2);
    __bf16* ctxB  = (__bf16*)alloc((size_t)M * 2048 * 2);
    float*  cosT  = (float*) alloc((size_t)SEQ * 128 * 4);
    float*  sinT  = (float*) alloc((size_t)SEQ * 128 * 4);

    cvt_rope<<<21504, 256, 0, stream>>>(hs, Wq, Wk, Wv, Wo,
                                        hsB, WqkvB, WqkvB + (size_t)2048 * 2048,
                                        WqkvB + (size_t)3072 * 2048, WoB, cosT, sinT);

    // fused QKV projection + RMSNorm + RoPE: 256 blocks (16x16 tiles of 256)
    gemm_qkv<<<256, 512, 0, stream>>>(hsB, WqkvB, qw, kw, cosT, sinT,
                                      Qb, Kbf, Vbf, M, 4096, DMODEL, 16);

    attn8<<<512, 256, 0, stream>>>(Qb, Kbf, Vbf, ctxB);

    // output projection: 256 blocks (16x16 tiles of 256x128)
    gemm_bt8n<<<256, 512, 0, stream>>>(ctxB, WoB, out, M, DMODEL, DMODEL, 16);
}

// Round 18
// 196.441 us; speedup vs baseline: 2.0905x; 1.0090x over previous
//
#include <hip/hip_runtime.h>
#include <hip/hip_bf16.h>

// ---------------------------------------------------------------------------
// Gemma sliding-window attention layer, MI355X round 18.
// = round-17 (198.2 us) + ILP in the fused norm/rope epilogue (unroll 2 on
// the row loop; two independent shfl-reduce chains in flight).
// All sync structures frozen.
// ---------------------------------------------------------------------------

typedef __bf16 bf16x8 __attribute__((ext_vector_type(8)));
typedef __bf16 bf16x4 __attribute__((ext_vector_type(4)));
typedef float f32x4 __attribute__((ext_vector_type(4)));

#define NB 2
#define SEQ 2048
#define DMODEL 2048
#define NH 8
#define NKV 4
#define DHEAD 256
#define SWIN 1024

#define AS1 __attribute__((address_space(1)))
#define AS3 __attribute__((address_space(3)))

static __device__ __forceinline__ void gload_lds16(const void* g, void* l) {
    __builtin_amdgcn_global_load_lds((const AS1 void*)g, (AS3 void*)l, 16, 0, 0);
}

static __device__ __forceinline__ bf16x4 tr16(const __bf16* p) {
    bf16x4 r;
    asm volatile("ds_read_b64_tr_b16 %0, %1" : "=v"(r) : "v"((const AS3 __bf16*)p));
    return r;
}

// ------------------- merged f32->bf16 convert + RoPE table ------------------
__global__ void cvt_rope(const float* __restrict__ s0, const float* __restrict__ s1,
                         const float* __restrict__ s2, const float* __restrict__ s3,
                         const float* __restrict__ s4, __bf16* __restrict__ d0,
                         __bf16* __restrict__ d1, __bf16* __restrict__ d2,
                         __bf16* __restrict__ d3, __bf16* __restrict__ d4,
                         float* __restrict__ cosT, float* __restrict__ sinT) {
    if (blockIdx.x >= 20480) {
        int idx = (blockIdx.x - 20480) * 256 + threadIdx.x;   // < 262144
        int s = idx >> 7, i = idx & 127;
        float fr = (float)s * __expf(-(float)i * 0.0719557843f);  // ln(1e4)/128
        cosT[idx] = cosf(fr);
        sinT[idx] = sinf(fr);
        return;
    }
    int i = blockIdx.x * 256 + threadIdx.x;      // covers exactly 5242880
    const float* src; __bf16* dst;
    if (i < 2097152) { src = s0; dst = d0; }
    else if (i < 3145728) { i -= 2097152; src = s1; dst = d1; }
    else if (i < 3670016) { i -= 3145728; src = s2; dst = d2; }
    else if (i < 4194304) { i -= 3670016; src = s3; dst = d3; }
    else                  { i -= 4194304; src = s4; dst = d4; }
    f32x4 v = ((const f32x4*)src)[i];
    bf16x4 o;
#pragma unroll
    for (int j = 0; j < 4; ++j) o[j] = (__bf16)v[j];
    ((bf16x4*)dst)[i] = o;
}

// --------- QKV GEMM 256x256, BK=64, 8-phase pipelined + fused norm/rope ----
__global__ __launch_bounds__(512, 2)
void gemm_qkv(const __bf16* __restrict__ A, const __bf16* __restrict__ B,
              const float* __restrict__ qw, const float* __restrict__ kw,
              const float* __restrict__ cosT, const float* __restrict__ sinT,
              __bf16* __restrict__ Qo, __bf16* __restrict__ Ko,
              __bf16* __restrict__ Vo, int M, int N, int K, int nbx) {
    __shared__ __align__(16) __bf16 smem[67584];       // 132 KB
    const int tid = threadIdx.x;
    const int wave = tid >> 6, lane = tid & 63;
    const int lo = lane & 15, hi = lane >> 4;
    const int wm = wave >> 2, wn = wave & 3;
    const int qq = (int)gridDim.x >> 3;
    const int swz = ((int)blockIdx.x & 7) * qq + ((int)blockIdx.x >> 3);
    const int bx = swz % nbx, by = swz / nbx;
    const int brow = by * 256;
    const int xr = lo & 7;

    int aoff[4];
#pragma unroll
    for (int i = 0; i < 4; ++i) {
        int n = i * 512 + tid, r = n >> 3, s = n & 7;
        aoff[i] = r * K + ((s ^ (r & 7)) << 3);   // pre-swizzled global source
    }
    const __bf16* Ab = A + (size_t)brow * K;
    const __bf16* Bb = B + (size_t)(bx * 256) * K;

    auto stgA = [&](int bsel, int kt, int h) {
        const __bf16* ga = Ab + kt * 64;
#pragma unroll
        for (int ii = 0; ii < 2; ++ii) {
            int i = h + ii * 2;
            gload_lds16(ga + aoff[i], (char*)(smem + bsel * 16384) + (i * 512 + wave * 64) * 16);
        }
    };
    auto stgB = [&](int bsel, int kt, int h) {
        const __bf16* gb = Bb + kt * 64;
#pragma unroll
        for (int i = 2 * h; i < 2 * h + 2; ++i)
            gload_lds16(gb + aoff[i], (char*)(smem + 32768 + bsel * 16384) + (i * 512 + wave * 64) * 16);
    };

    f32x4 acc[8][4] = {};
    const int nt = K >> 6;

    stgA(0, 0, 0); stgA(0, 0, 1); stgB(0, 0, 0); stgB(0, 0, 1);
    stgA(1, 1, 0); stgA(1, 1, 1); stgB(1, 1, 0); stgB(1, 1, 1);
    asm volatile("s_waitcnt vmcnt(8)" ::: "memory");   // tile0 landed
    __builtin_amdgcn_s_barrier();

    for (int t = 0; t < nt; ++t) {
        const int buf = t & 1;
        const bool pre = (t + 2 < nt);
        const __bf16* sa = smem + buf * 16384;
        const __bf16* sb = smem + 32768 + buf * 16384;
        bf16x8 af[8], b0[4], b1[4];
        // ---- g0: ds_read A rows wm*128+0..63 (slots {0,2}) + B-nh0; MFMA Q0
#pragma unroll
        for (int m = 0; m < 4; ++m)
#pragma unroll
            for (int ks = 0; ks < 2; ++ks)
                af[m * 2 + ks] = *(const bf16x8*)&sa[(wm * 128 + m * 16 + lo) * 64 + (((ks * 4 + hi) ^ xr) << 3)];
#pragma unroll
        for (int n = 0; n < 2; ++n)
#pragma unroll
            for (int ks = 0; ks < 2; ++ks)
                b0[n * 2 + ks] = *(const bf16x8*)&sb[(wn * 64 + n * 16 + lo) * 64 + (((ks * 4 + hi) ^ xr) << 3)];
        __builtin_amdgcn_sched_barrier(0);
        __builtin_amdgcn_s_barrier();
        __builtin_amdgcn_s_setprio(1);
#pragma unroll
        for (int m = 0; m < 4; ++m)
#pragma unroll
            for (int n = 0; n < 2; ++n)
#pragma unroll
                for (int ks = 0; ks < 2; ++ks)
                    acc[m][n] = __builtin_amdgcn_mfma_f32_16x16x32_bf16(af[m * 2 + ks], b0[n * 2 + ks], acc[m][n], 0, 0, 0);
        __builtin_amdgcn_s_setprio(0);
        __builtin_amdgcn_sched_barrier(0);
        __builtin_amdgcn_s_barrier();
        // ---- g1: ds_read B-nh1; stage A-set0(t+2); MFMA Q1
#pragma unroll
        for (int n = 0; n < 2; ++n)
#pragma unroll
            for (int ks = 0; ks < 2; ++ks)
                b1[n * 2 + ks] = *(const bf16x8*)&sb[(wn * 64 + (n + 2) * 16 + lo) * 64 + (((ks * 4 + hi) ^ xr) << 3)];
        if (pre) stgA(buf, t + 2, 0);
        __builtin_amdgcn_sched_barrier(0);
        __builtin_amdgcn_s_barrier();
        __builtin_amdgcn_s_setprio(1);
#pragma unroll
        for (int m = 0; m < 4; ++m)
#pragma unroll
            for (int n = 0; n < 2; ++n)
#pragma unroll
                for (int ks = 0; ks < 2; ++ks)
                    acc[m][n + 2] = __builtin_amdgcn_mfma_f32_16x16x32_bf16(af[m * 2 + ks], b1[n * 2 + ks], acc[m][n + 2], 0, 0, 0);
        __builtin_amdgcn_s_setprio(0);
        __builtin_amdgcn_sched_barrier(0);
        __builtin_amdgcn_s_barrier();
        // ---- g2: ds_read A rows wm*128+64..127 (slots {1,3}); stage B{2,3}(t+2); MFMA Q2
#pragma unroll
        for (int m = 0; m < 4; ++m)
#pragma unroll
            for (int ks = 0; ks < 2; ++ks)
                af[m * 2 + ks] = *(const bf16x8*)&sa[(wm * 128 + (m + 4) * 16 + lo) * 64 + (((ks * 4 + hi) ^ xr) << 3)];
        if (pre) stgB(buf, t + 2, 1);
        __builtin_amdgcn_sched_barrier(0);
        __builtin_amdgcn_s_barrier();
        __builtin_amdgcn_s_setprio(1);
#pragma unroll
        for (int m = 0; m < 4; ++m)
#pragma unroll
            for (int n = 0; n < 2; ++n)
#pragma unroll
                for (int ks = 0; ks < 2; ++ks)
                    acc[m + 4][n + 2] = __builtin_amdgcn_mfma_f32_16x16x32_bf16(af[m * 2 + ks], b1[n * 2 + ks], acc[m + 4][n + 2], 0, 0, 0);
        __builtin_amdgcn_s_setprio(0);
        __builtin_amdgcn_sched_barrier(0);
        __builtin_amdgcn_s_barrier();
        // ---- g3: stage A-set1{1,3}+B{0,1}(t+2); MFMA Q3; vmcnt(8)
        if (pre) { stgA(buf, t + 2, 1); stgB(buf, t + 2, 0); }
        __builtin_amdgcn_sched_barrier(0);
        __builtin_amdgcn_s_setprio(1);
#pragma unroll
        for (int m = 0; m < 4; ++m)
#pragma unroll
            for (int n = 0; n < 2; ++n)
#pragma unroll
                for (int ks = 0; ks < 2; ++ks)
                    acc[m + 4][n] = __builtin_amdgcn_mfma_f32_16x16x32_bf16(af[m * 2 + ks], b0[n * 2 + ks], acc[m + 4][n], 0, 0, 0);
        __builtin_amdgcn_s_setprio(0);
        if (pre) asm volatile("s_waitcnt vmcnt(8)" ::: "memory");
        else     asm volatile("s_waitcnt vmcnt(0)" ::: "memory");
        __builtin_amdgcn_sched_barrier(0);
        __builtin_amdgcn_s_barrier();
    }

    // ---- fused epilogue -----------------------------------------------------
    __syncthreads();                      // K-loop fully retired; smem reusable
    {
#pragma unroll
        for (int m = 0; m < 8; ++m)
#pragma unroll
            for (int n = 0; n < 4; ++n) {
                int lr = wm * 128 + m * 16 + hi * 4;
                int lc = wn * 64 + n * 16 + lo;
#pragma unroll
                for (int j = 0; j < 4; ++j)
                    smem[(lr + j) * 264 + lc] = (__bf16)acc[m][n][j];
            }
        __syncthreads();

        const bool isq = bx < 8;
        const bool isv = bx >= 12;
        float w4[4];
        if (!isv) {
            const float* wp = isq ? qw : kw;
#pragma unroll
            for (int j = 0; j < 4; ++j) w4[j] = 1.f + wp[lane * 4 + j];
        }
        __bf16* hbase = isq ? Qo : (isv ? Vo : Ko);
        const int hidx = isq ? bx : (isv ? bx - 12 : bx - 8);
        const int nheads = isq ? NH : NKV;

#pragma unroll 2
        for (int rr = 0; rr < 32; ++rr) {
            int lr = wave * 32 + rr;
            int gs = brow + lr;
            int bb = gs >> 11, s = gs & (SEQ - 1);
            bf16x4 xb = *(const bf16x4*)&smem[lr * 264 + lane * 4];
            bf16x4 ov;
            if (isv) {
                ov = xb;
            } else {
                float x[4];
#pragma unroll
                for (int j = 0; j < 4; ++j) x[j] = (float)xb[j];
                float ss = x[0] * x[0] + x[1] * x[1] + x[2] * x[2] + x[3] * x[3];
#pragma unroll
                for (int d2 = 1; d2 < 64; d2 <<= 1) ss += __shfl_xor(ss, d2);
                float scale = rsqrtf(ss * (1.f / DHEAD) + 1e-6f);
                float nx[4];
#pragma unroll
                for (int j = 0; j < 4; ++j) nx[j] = x[j] * scale * w4[j];
                f32x4 cos4 = *(const f32x4*)&cosT[s * 128 + (lane & 31) * 4];
                f32x4 sin4 = *(const f32x4*)&sinT[s * 128 + (lane & 31) * 4];
#pragma unroll
                for (int j = 0; j < 4; ++j) {
                    float other = __shfl_xor(nx[j], 32);
                    float rot = (lane < 32) ? -other : other;
                    float v = nx[j] * cos4[j] + rot * sin4[j];
                    if (isq) v *= 0.0625f;   // SCALE folded into q
                    ov[j] = (__bf16)v;
                }
            }
            __bf16* dst = hbase + ((size_t)(bb * nheads + hidx) * SEQ + s) * DHEAD;
            *(bf16x4*)&dst[lane * 4] = ov;
        }
    }
}

// --------- GEMM 256x128, BK=64, out-proj (full machine, frozen) ------------
__global__ __launch_bounds__(512, 2)
void gemm_bt8n(const __bf16* __restrict__ A, const __bf16* __restrict__ B,
               float* __restrict__ C, int M, int N, int K, int nbx) {
    __shared__ __align__(16) __bf16 sA[2][256 * 64];   // 64 KB
    __shared__ __align__(16) __bf16 sB[2][128 * 64];   // 32 KB
    const int tid = threadIdx.x;
    const int wave = tid >> 6, lane = tid & 63;
    const int lo = lane & 15, hi = lane >> 4;
    const int wm = wave >> 1, wn = wave & 1;
    const int qq = (int)gridDim.x >> 3;
    const int swz = ((int)blockIdx.x & 7) * qq + ((int)blockIdx.x >> 3);
    const int bx = swz % nbx, by = swz / nbx;
    const int brow = by * 256, bcol = bx * 128;
    const int xr = lo & 7;

    int aoff[4], boff[2];
#pragma unroll
    for (int i = 0; i < 4; ++i) {
        int n = i * 512 + tid, r = n >> 3, s = n & 7;
        aoff[i] = r * K + ((s ^ (r & 7)) << 3);
    }
#pragma unroll
    for (int i = 0; i < 2; ++i) {
        int n = i * 512 + tid, r = n >> 3, s = n & 7;
        boff[i] = r * K + ((s ^ (r & 7)) << 3);
    }
    const __bf16* Ab = A + (size_t)brow * K;
    const __bf16* Bb = B + (size_t)bcol * K;

    auto stgAall = [&](int bsel, int kt) {
        const __bf16* ga = Ab + kt * 64;
#pragma unroll
        for (int i = 0; i < 4; ++i)
            gload_lds16(ga + aoff[i], (char*)&sA[bsel][0] + (i * 512 + wave * 64) * 16);
    };
    auto stgBall = [&](int bsel, int kt) {
        const __bf16* gb = Bb + kt * 64;
#pragma unroll
        for (int i = 0; i < 2; ++i)
            gload_lds16(gb + boff[i], (char*)&sB[bsel][0] + (i * 512 + wave * 64) * 16);
    };

    f32x4 acc[4][4] = {};
    const int nt = K >> 6;

    stgAall(0, 0); stgBall(0, 0);      // 6 loads (tile0)
    stgAall(1, 1); stgBall(1, 1);      // 6 loads (tile1)
    asm volatile("s_waitcnt vmcnt(6)" ::: "memory");   // tile0 landed
    __builtin_amdgcn_s_barrier();

    for (int t = 0; t < nt; ++t) {
        const int buf = t & 1;
        const bool pre = (t + 2 < nt);
        const __bf16* sa = &sA[buf][0];
        const __bf16* sb = &sB[buf][0];
        bf16x8 af[4], b0[4], b1[4];
        // ---- g0: ds_read A m01 + B n01; MFMA Q0
#pragma unroll
        for (int m = 0; m < 2; ++m)
#pragma unroll
            for (int ks = 0; ks < 2; ++ks)
                af[m * 2 + ks] = *(const bf16x8*)&sa[(wm * 64 + m * 16 + lo) * 64 + (((ks * 4 + hi) ^ xr) << 3)];
#pragma unroll
        for (int n = 0; n < 2; ++n)
#pragma unroll
            for (int ks = 0; ks < 2; ++ks)
                b0[n * 2 + ks] = *(const bf16x8*)&sb[(wn * 64 + n * 16 + lo) * 64 + (((ks * 4 + hi) ^ xr) << 3)];
        __builtin_amdgcn_sched_barrier(0);
        __builtin_amdgcn_s_barrier();
        __builtin_amdgcn_s_setprio(1);
#pragma unroll
        for (int m = 0; m < 2; ++m)
#pragma unroll
            for (int n = 0; n < 2; ++n)
#pragma unroll
                for (int ks = 0; ks < 2; ++ks)
                    acc[m][n] = __builtin_amdgcn_mfma_f32_16x16x32_bf16(af[m * 2 + ks], b0[n * 2 + ks], acc[m][n], 0, 0, 0);
        __builtin_amdgcn_s_setprio(0);
        __builtin_amdgcn_sched_barrier(0);
        __builtin_amdgcn_s_barrier();
        // ---- g1: ds_read B n23; MFMA Q1
#pragma unroll
        for (int n = 0; n < 2; ++n)
#pragma unroll
            for (int ks = 0; ks < 2; ++ks)
                b1[n * 2 + ks] = *(const bf16x8*)&sb[(wn * 64 + (n + 2) * 16 + lo) * 64 + (((ks * 4 + hi) ^ xr) << 3)];
        __builtin_amdgcn_sched_barrier(0);
        __builtin_amdgcn_s_barrier();
        __builtin_amdgcn_s_setprio(1);
#pragma unroll
        for (int m = 0; m < 2; ++m)
#pragma unroll
            for (int n = 0; n < 2; ++n)
#pragma unroll
                for (int ks = 0; ks < 2; ++ks)
                    acc[m][n + 2] = __builtin_amdgcn_mfma_f32_16x16x32_bf16(af[m * 2 + ks], b1[n * 2 + ks], acc[m][n + 2], 0, 0, 0);
        __builtin_amdgcn_s_setprio(0);
        __builtin_amdgcn_sched_barrier(0);
        __builtin_amdgcn_s_barrier();
        // ---- g2: ds_read A m23; stage B(t+2); MFMA Q2
#pragma unroll
        for (int m = 0; m < 2; ++m)
#pragma unroll
            for (int ks = 0; ks < 2; ++ks)
                af[m * 2 + ks] = *(const bf16x8*)&sa[(wm * 64 + (m + 2) * 16 + lo) * 64 + (((ks * 4 + hi) ^ xr) << 3)];
        if (pre) stgBall(buf, t + 2);
        __builtin_amdgcn_sched_barrier(0);
        __builtin_amdgcn_s_barrier();
        __builtin_amdgcn_s_setprio(1);
#pragma unroll
        for (int m = 0; m < 2; ++m)
#pragma unroll
            for (int n = 0; n < 2; ++n)
#pragma unroll
                for (int ks = 0; ks < 2; ++ks)
                    acc[m + 2][n + 2] = __builtin_amdgcn_mfma_f32_16x16x32_bf16(af[m * 2 + ks], b1[n * 2 + ks], acc[m + 2][n + 2], 0, 0, 0);
        __builtin_amdgcn_s_setprio(0);
        __builtin_amdgcn_sched_barrier(0);
        __builtin_amdgcn_s_barrier();
        // ---- g3: stage A(t+2); MFMA Q3; vmcnt(6)
        if (pre) stgAall(buf, t + 2);
        __builtin_amdgcn_sched_barrier(0);
        __builtin_amdgcn_s_setprio(1);
#pragma unroll
        for (int m = 0; m < 2; ++m)
#pragma unroll
            for (int n = 0; n < 2; ++n)
#pragma unroll
                for (int ks = 0; ks < 2; ++ks)
                    acc[m + 2][n] = __builtin_amdgcn_mfma_f32_16x16x32_bf16(af[m * 2 + ks], b0[n * 2 + ks], acc[m + 2][n], 0, 0, 0);
        __builtin_amdgcn_s_setprio(0);
        if (pre) asm volatile("s_waitcnt vmcnt(6)" ::: "memory");
        else     asm volatile("s_waitcnt vmcnt(0)" ::: "memory");
        __builtin_amdgcn_sched_barrier(0);
        __builtin_amdgcn_s_barrier();
    }

#pragma unroll
    for (int m = 0; m < 4; ++m) {
        int row = brow + wm * 64 + m * 16 + hi * 4;
#pragma unroll
        for (int n = 0; n < 4; ++n) {
            float* cp = C + (size_t)row * N + bcol + wn * 64 + n * 16 + lo;
#pragma unroll
            for (int j = 0; j < 4; ++j)
                cp[(size_t)j * N] = acc[m][n][j];
        }
    }
}

// ------------------ flash attention v8 (round-13 optimum, frozen) ----------
__global__ __launch_bounds__(256)
void attn8(const __bf16* __restrict__ Q, const __bf16* __restrict__ Kb,
           const __bf16* __restrict__ Vb, __bf16* __restrict__ ctx) {
    const int bid = blockIdx.x;
    const int bk = bid & 7;            // XCD grouping: same (b,kh) -> same XCD
    const int qt = 63 - (bid >> 3);    // heavy blocks dispatch first
    const int b = bk >> 2, kh = bk & 3;
    const int q0 = qt * 32;
    const int tid = threadIdx.x;
    const int wave = tid >> 6, lane = tid & 63;
    const int lo = lane & 15, hi = lane >> 4;
    const int hsel = wave >> 1, qsub = wave & 1;
    const int h = kh * 2 + hsel;
    const int qbase = q0 + qsub * 16;
    const int q = qbase + lo;

    __shared__ __align__(16) __bf16 kbuf[2][32 * 256];   // 2 x 16 KB
    __shared__ __align__(16) __bf16 vbuf[32 * 256];      // 16 KB single

    const __bf16* Qp = Q + ((size_t)(b * NH + h) * SEQ + qbase) * DHEAD;
    const __bf16* Kp = Kb + (size_t)(b * NKV + kh) * SEQ * DHEAD;
    const __bf16* Vp = Vb + (size_t)(b * NKV + kh) * SEQ * DHEAD;

    int koff[4], voff[4];
#pragma unroll
    for (int i = 0; i < 4; ++i) {
        int n = i * 256 + tid;                 // 16B slot index
        int r = n >> 5, c = n & 31;
        koff[i] = r * 256 + ((c ^ (r & 7)) << 3);
        int st = n >> 3, w = n & 7;
        int vk = (st & 7) * 4 + (w >> 1);
        int vd = (st >> 3) * 16 + (w & 1) * 8;
        voff[i] = vk * 256 + vd;
    }

    auto stageK = [&](int bsel, int c0) {
        const __bf16* kg = Kp + (size_t)c0 * DHEAD;
        char* kd = (char*)&kbuf[bsel][0] + wave * 1024;
#pragma unroll
        for (int i = 0; i < 4; ++i) gload_lds16(kg + koff[i], kd + i * 4096);
    };
    auto stageV = [&](int c0) {
        const __bf16* vg = Vp + (size_t)c0 * DHEAD;
        char* vd = (char*)&vbuf[0] + wave * 1024;
#pragma unroll
        for (int i = 0; i < 4; ++i) gload_lds16(vg + voff[i], vd + i * 4096);
    };

    bf16x8 qf[8];
#pragma unroll
    for (int dc = 0; dc < 8; ++dc)
        qf[dc] = *(const bf16x8*)(Qp + (size_t)lo * DHEAD + dc * 32 + hi * 8);

    f32x4 o[16] = {};
    float m = -3e38f, l = 0.f;

    int kstart = q0 - SWIN; if (kstart < 0) kstart = 0;
    const int nt = (q0 + 32 - kstart) >> 5;

    stageK(0, kstart);
    asm volatile("s_waitcnt vmcnt(0)" ::: "memory");   // qf + own K(0): count exact
    int buf = 0;
    for (int t = 0; t < nt; ++t) {
        const int c0 = kstart + t * 32;
        const bool pre = (t + 1 < nt);
        stageV(c0);                          // vbuf has no readers (post end-barrier)
        if (pre) stageK(buf ^ 1, c0 + 32);
        // K(t) resident for all waves: drain to just {V(t), K(t+1)}
        if (pre) asm volatile("s_waitcnt vmcnt(8)" ::: "memory");
        else     asm volatile("s_waitcnt vmcnt(4)" ::: "memory");
        __builtin_amdgcn_sched_barrier(0);
        __builtin_amdgcn_s_barrier();
        __builtin_amdgcn_sched_barrier(0);   // pin QK^T ds_reads below barrier

        // ---- QK^T (swapped): keys c0+hi*4+j (sc0) / +16 (sc1), q = lo
        f32x4 sc0 = {}, sc1 = {};
        const __bf16* kb0 = &kbuf[buf][0];
        __builtin_amdgcn_s_setprio(1);
#pragma unroll
        for (int dc = 0; dc < 8; ++dc) {
            int u = dc * 4 + hi;
            bf16x8 kfa = *(const bf16x8*)&kb0[lo * 256 + ((u ^ (lo & 7)) << 3)];
            bf16x8 kfb = *(const bf16x8*)&kb0[(16 + lo) * 256 + ((u ^ ((16 + lo) & 7)) << 3)];
            sc0 = __builtin_amdgcn_mfma_f32_16x16x32_bf16(kfa, qf[dc], sc0, 0, 0, 0);
            sc1 = __builtin_amdgcn_mfma_f32_16x16x32_bf16(kfb, qf[dc], sc1, 0, 0, 0);
        }
        __builtin_amdgcn_s_setprio(0);

        // ---- mask + lane-parallel online softmax (state keyed q = lo)
        float s8[8];
#pragma unroll
        for (int j = 0; j < 4; ++j) {
            int ka = c0 + hi * 4 + j;
            int kb2 = ka + 16;
            s8[j]     = (ka <= q && q - ka < SWIN) ? sc0[j] : -1e30f;
            s8[4 + j] = (kb2 <= q && q - kb2 < SWIN) ? sc1[j] : -1e30f;
        }
        float pm = s8[0];
#pragma unroll
        for (int i = 1; i < 8; ++i) pm = fmaxf(pm, s8[i]);
        pm = fmaxf(pm, __shfl_xor(pm, 16));
        pm = fmaxf(pm, __shfl_xor(pm, 32));
        if (__any(pm > m + 8.f)) {             // T13 defer-max
            float mn = fmaxf(m, pm);
            float corr = __expf(m - mn);
            l *= corr;
#pragma unroll
            for (int dt = 0; dt < 16; ++dt) o[dt] *= corr;
            m = mn;
        }
        float p8[8], ps = 0.f;
#pragma unroll
        for (int i = 0; i < 8; ++i) {
            float e = __expf(s8[i] - m);
            p8[i] = (s8[i] > -9e29f) ? e : 0.f;
            ps += p8[i];
        }
        ps += __shfl_xor(ps, 16);
        ps += __shfl_xor(ps, 32);
        l += ps;

        bf16x8 paf;
#pragma unroll
        for (int i = 0; i < 8; ++i) paf[i] = (__bf16)p8[i];

        // V(t) resident for all waves: drain to just {K(t+1)}
        if (pre) asm volatile("s_waitcnt vmcnt(4)" ::: "memory");
        else     asm volatile("s_waitcnt vmcnt(0)" ::: "memory");
        __builtin_amdgcn_sched_barrier(0);
        __builtin_amdgcn_s_barrier();
        __builtin_amdgcn_sched_barrier(0);   // pin tr16 reads below barrier

        // ---- PV: flat-issue all 32 tr16 (order pinned per 8-read chunk),
        //      then counted lgkmcnt per 4-MFMA group (15 = field max).
        const __bf16* vb0 = &vbuf[0];
        bf16x4 t0[16], t1[16];
#pragma unroll
        for (int dq = 0; dq < 4; ++dq) {
#pragma unroll
            for (int u = 0; u < 4; ++u) {
                int dt = dq * 4 + u;
                t0[dt] = tr16(vb0 + (dt * 8 + hi) * 64 + lo * 4);       // k 0..3
                t1[dt] = tr16(vb0 + (dt * 8 + 4 + hi) * 64 + lo * 4);   // k 4..7
            }
            __builtin_amdgcn_sched_barrier(0);   // pin chunk issue order
        }
#pragma unroll
        for (int dq = 0; dq < 4; ++dq) {
            if (dq == 0)      asm volatile("s_waitcnt lgkmcnt(15)" ::: "memory");
            else if (dq == 1) asm volatile("s_waitcnt lgkmcnt(15)" ::: "memory");
            else if (dq == 2) asm volatile("s_waitcnt lgkmcnt(8)"  ::: "memory");
            else              asm volatile("s_waitcnt lgkmcnt(0)"  ::: "memory");
            __builtin_amdgcn_sched_barrier(0);
            __builtin_amdgcn_s_setprio(1);
#pragma unroll
            for (int u = 0; u < 4; ++u) {
                int dt = dq * 4 + u;
                bf16x8 vf;
#pragma unroll
                for (int j = 0; j < 4; ++j) { vf[j] = t0[dt][j]; vf[4 + j] = t1[dt][j]; }
                o[dt] = __builtin_amdgcn_mfma_f32_16x16x32_bf16(vf, paf, o[dt], 0, 0, 0);
            }
            __builtin_amdgcn_s_setprio(0);
        }
        __builtin_amdgcn_sched_barrier(0);
        __builtin_amdgcn_s_barrier();        // raw WAR barrier: PV reads retired
        __builtin_amdgcn_sched_barrier(0);
        buf ^= 1;
    }

    const float invl = 1.0f / l;
    __bf16* cp = ctx + ((size_t)(b * SEQ + q)) * (NH * DHEAD) + h * DHEAD;
#pragma unroll
    for (int dt = 0; dt < 16; ++dt) {
        bf16x4 w;
#pragma unroll
        for (int j = 0; j < 4; ++j) w[j] = (__bf16)(o[dt][j] * invl);
        *(bf16x4*)&cp[dt * 16 + hi * 4] = w;
    }
}

// ---------------------------------------------------------------------------
extern "C" void kernel_launch(void* const* d_in, const int* in_sizes, int n_in,
                              void* d_out, int out_size, void* d_ws, size_t ws_size,
                              hipStream_t stream) {
    const float* hs = (const float*)d_in[0];
    const float* Wq = (const float*)d_in[1];
    const float* Wk = (const float*)d_in[2];
    const float* Wv = (const float*)d_in[3];
    const float* Wo = (const float*)d_in[4];
    const float* qw = (const float*)d_in[5];
    const float* kw = (const float*)d_in[6];
    float* out = (float*)d_out;

    char* ws = (char*)d_ws;
    size_t off = 0;
    auto alloc = [&](size_t bytes) {
        char* p = ws + off;
        off += (bytes + 255) & ~(size_t)255;
        return p;
    };
    const int M = NB * SEQ;                       // 4096
    __bf16* hsB   = (__bf16*)alloc((size_t)M * DMODEL * 2);
    __bf16* WqkvB = (__bf16*)alloc((size_t)4096 * DMODEL * 2);
    __bf16* WoB   = (__bf16*)alloc((size_t)DMODEL * DMODEL * 2);
    __bf16* Qb    = (__bf16*)alloc((size_t)M * 2048 * 2);
    __bf16* Kbf   = (__bf16*)alloc((size_t)M * 1024 * 2);
    __bf16* Vbf   = (__bf16*)alloc((size_t)M * 1024 * 2);
    __bf16* ctxB  = (__bf16*)alloc((size_t)M * 2048 * 2);
    float*  cosT  = (float*) alloc((size_t)SEQ * 128 * 4);
    float*  sinT  = (float*) alloc((size_t)SEQ * 128 * 4);

    cvt_rope<<<21504, 256, 0, stream>>>(hs, Wq, Wk, Wv, Wo,
                                        hsB, WqkvB, WqkvB + (size_t)2048 * 2048,
                                        WqkvB + (size_t)3072 * 2048, WoB, cosT, sinT);

    // fused QKV projection + RMSNorm + RoPE: 256 blocks (16x16 tiles of 256)
    gemm_qkv<<<256, 512, 0, stream>>>(hsB, WqkvB, qw, kw, cosT, sinT,
                                      Qb, Kbf, Vbf, M, 4096, DMODEL, 16);

    attn8<<<512, 256, 0, stream>>>(Qb, Kbf, Vbf, ctxB);

    // output projection: 256 blocks (16x16 tiles of 256x128)
    gemm_bt8n<<<256, 512, 0, stream>>>(ctxB, WoB, out, M, DMODEL, DMODEL, 16);
}